// Round 1
// baseline (1317.923 us; speedup 1.0000x reference)
//
#include <hip/hip_runtime.h>
#include <math.h>

#define NN 20000
#define EE 320000
#define GG 64

// ---------------------------------------------------------------------------
// CSR construction: count -> scan -> fill
// ---------------------------------------------------------------------------
__global__ __launch_bounds__(256) void count_kernel(const int* __restrict__ dst,
                                                    int* __restrict__ cnt, int E) {
    int e = blockIdx.x * 256 + threadIdx.x;
    if (e < E) atomicAdd(&cnt[dst[e]], 1);
}

// single-block inclusive scan over n counts; off[0..n] = exclusive offsets,
// cnt[i] rewritten to exclusive offset (used as placement cursor)
__global__ __launch_bounds__(1024) void scan_kernel(int* __restrict__ cnt,
                                                    int* __restrict__ off, int n) {
    __shared__ int buf[1024];
    __shared__ int carry_s;
    int tid = threadIdx.x;
    if (tid == 0) { carry_s = 0; off[0] = 0; }
    __syncthreads();
    for (int base = 0; base < n; base += 1024) {
        int idx = base + tid;
        int val = (idx < n) ? cnt[idx] : 0;
        buf[tid] = val;
        __syncthreads();
        int x = val;
        for (int s = 1; s < 1024; s <<= 1) {
            int y = (tid >= s) ? buf[tid - s] : 0;
            __syncthreads();
            x += y;
            buf[tid] = x;
            __syncthreads();
        }
        int carry = carry_s;
        if (idx < n) {
            off[idx + 1] = carry + x;       // inclusive + carry
            cnt[idx] = carry + x - val;     // exclusive offset -> cursor
        }
        __syncthreads();
        if (tid == 1023) carry_s = carry + x;
        __syncthreads();
    }
}

__global__ __launch_bounds__(256) void fill_kernel(const int* __restrict__ src,
                                                   const int* __restrict__ dst,
                                                   int* __restrict__ cursor,
                                                   int* __restrict__ csr_src, int E) {
    int e = blockIdx.x * 256 + threadIdx.x;
    if (e < E) {
        int p = atomicAdd(&cursor[dst[e]], 1);
        csr_src[p] = src[e];
    }
}

// ---------------------------------------------------------------------------
// Mean aggregation: mean[i,f] = sum_{j in nbr(i)} x[src_j, f] / max(deg,1)
// one block (F threads) per node
// ---------------------------------------------------------------------------
__global__ __launch_bounds__(128) void mean_kernel(const float* __restrict__ x,
                                                   const int* __restrict__ off,
                                                   const int* __restrict__ csr_src,
                                                   float* __restrict__ mean, int F) {
    int i = blockIdx.x;
    int f = threadIdx.x;
    int e0 = off[i], e1 = off[i + 1];
    float s = 0.f;
    for (int e = e0; e < e1; e++) s += x[(size_t)csr_src[e] * F + f];
    int deg = e1 - e0;
    mean[(size_t)i * F + f] = (deg > 0) ? s / (float)deg : 0.f;
}

// ---------------------------------------------------------------------------
// fp32 GEMM: C[M,Nc] (from A[M,K] @ W[K,Nc]) with fused epilogue
// MODE 0: C = A@W + bias
// MODE 1: C = relu(C + A@W)           (no bias)
// MODE 2: C = relu(A@W + bias)
// MODE 3: C = sigmoid(A@W + bias)
// 64x64 tile, 256 threads, 4x4 microtile, BK=16. Nc%64==0, K%16==0 required.
// ---------------------------------------------------------------------------
template <int MODE>
__global__ __launch_bounds__(256) void gemm_kernel(const float* __restrict__ A,
                                                   const float* __restrict__ W,
                                                   const float* __restrict__ bias,
                                                   float* __restrict__ C,
                                                   int M, int K, int Nc) {
    __shared__ float As[16][65];  // [k][m]
    __shared__ float Bs[16][65];  // [k][n]
    int t = threadIdx.x;
    int tx = t & 15, ty = t >> 4;
    int bm = blockIdx.y * 64, bn = blockIdx.x * 64;
    float acc[4][4] = {};
    for (int kk = 0; kk < K; kk += 16) {
        #pragma unroll
        for (int i = 0; i < 4; i++) {
            int e = i * 256 + t;
            int m = e >> 4, kq = e & 15;
            int gm = bm + m;
            As[kq][m] = (gm < M) ? A[(size_t)gm * K + kk + kq] : 0.f;
        }
        #pragma unroll
        for (int i = 0; i < 4; i++) {
            int e = i * 256 + t;
            int kq = e >> 6, n = e & 63;
            Bs[kq][n] = W[(size_t)(kk + kq) * Nc + bn + n];
        }
        __syncthreads();
        #pragma unroll
        for (int j = 0; j < 16; j++) {
            float a[4], b[4];
            #pragma unroll
            for (int i = 0; i < 4; i++) a[i] = As[j][ty * 4 + i];
            #pragma unroll
            for (int i = 0; i < 4; i++) b[i] = Bs[j][tx * 4 + i];
            #pragma unroll
            for (int i = 0; i < 4; i++)
                #pragma unroll
                for (int jj = 0; jj < 4; jj++) acc[i][jj] += a[i] * b[jj];
        }
        __syncthreads();
    }
    #pragma unroll
    for (int i = 0; i < 4; i++) {
        int gm = bm + ty * 4 + i;
        if (gm >= M) continue;
        #pragma unroll
        for (int jj = 0; jj < 4; jj++) {
            int gn = bn + tx * 4 + jj;
            float val = acc[i][jj];
            if (MODE == 0 || MODE == 2 || MODE == 3) val += bias[gn];
            if (MODE == 1) val += C[(size_t)gm * Nc + gn];
            if (MODE == 1 || MODE == 2) val = fmaxf(val, 0.f);
            if (MODE == 3) val = 1.f / (1.f + expf(-val));
            C[(size_t)gm * Nc + gn] = val;
        }
    }
}

template <int MODE>
static void launch_gemm(const float* A, const float* W, const float* bias, float* C,
                        int M, int K, int Nc, hipStream_t st) {
    dim3 grid(Nc / 64, (M + 63) / 64);
    hipLaunchKernelGGL((gemm_kernel<MODE>), grid, dim3(256), 0, st, A, W, bias, C, M, K, Nc);
}

// ---------------------------------------------------------------------------
// Per-node attention (TransformerConv): out[i] = relu(skip[i] + softmax-agg)
// block = 256 threads = 8 heads x 32 dims; online softmax over neighbors.
// `out` holds skip (x@ws+bs) on entry; overwritten with final result.
// ---------------------------------------------------------------------------
__global__ __launch_bounds__(256) void attn_kernel(const float* __restrict__ q,
                                                   const float* __restrict__ k,
                                                   const float* __restrict__ v,
                                                   const int* __restrict__ off,
                                                   const int* __restrict__ csr_src,
                                                   float* __restrict__ out) {
    int i = blockIdx.x;
    int tid = threadIdx.x;  // h = tid>>5, d = tid&31
    float qv = q[(size_t)i * 256 + tid];
    int e0 = off[i], e1 = off[i + 1];
    float m = -INFINITY, l = 0.f, acc = 0.f;
    for (int e = e0; e < e1; e++) {
        int s = csr_src[e];
        float kv = k[(size_t)s * 256 + tid];
        float prod = qv * kv;
        #pragma unroll
        for (int w = 16; w >= 1; w >>= 1) prod += __shfl_xor(prod, w, 32);
        float logit = prod * 0.17677669529663687f;  // 1/sqrt(32)
        float mn = fmaxf(m, logit);
        float esc = expf(m - mn);
        float p = expf(logit - mn);
        l = l * esc + p;
        acc = acc * esc + p * v[(size_t)s * 256 + tid];
        m = mn;
    }
    float res = (l > 0.f) ? acc / l : 0.f;
    float val = res + out[(size_t)i * 256 + tid];
    out[(size_t)i * 256 + tid] = fmaxf(val, 0.f);
}

// ---------------------------------------------------------------------------
// Global max pool over sorted batch: out[g,f] = max over nodes in group g.
// sigmoid outputs are positive -> int-bitcast atomicMax is monotone.
// out must be zero-initialized (all groups nonempty w.h.p.; values > 0).
// ---------------------------------------------------------------------------
__global__ __launch_bounds__(128) void pool_kernel(const float* __restrict__ hfin,
                                                   const int* __restrict__ batch,
                                                   float* __restrict__ out) {
    int f = threadIdx.x;
    int i0 = blockIdx.x * 64;
    int i1 = i0 + 64;
    if (i1 > NN) i1 = NN;
    int cur_g = -1;
    float cur_max = 0.f;
    for (int i = i0; i < i1; i++) {
        int g = batch[i];
        float val = hfin[(size_t)i * 128 + f];
        if (g != cur_g) {
            if (cur_g >= 0) atomicMax((int*)&out[cur_g * 128 + f], __float_as_int(cur_max));
            cur_g = g;
            cur_max = val;
        } else {
            cur_max = fmaxf(cur_max, val);
        }
    }
    if (cur_g >= 0) atomicMax((int*)&out[cur_g * 128 + f], __float_as_int(cur_max));
}

// ---------------------------------------------------------------------------
extern "C" void kernel_launch(void* const* d_in, const int* in_sizes, int n_in,
                              void* d_out, int out_size, void* d_ws, size_t ws_size,
                              hipStream_t stream) {
    const float* x      = (const float*)d_in[0];
    const int*   ei     = (const int*)d_in[1];
    const int*   batch  = (const int*)d_in[2];
    const float* s1_wl  = (const float*)d_in[3];
    const float* s1_bl  = (const float*)d_in[4];
    const float* s1_wr  = (const float*)d_in[5];
    const float* s2_wl  = (const float*)d_in[6];
    const float* s2_bl  = (const float*)d_in[7];
    const float* s2_wr  = (const float*)d_in[8];
    const float* t1_wq  = (const float*)d_in[9];
    const float* t1_bq  = (const float*)d_in[10];
    const float* t1_wk  = (const float*)d_in[11];
    const float* t1_bk  = (const float*)d_in[12];
    const float* t1_wv  = (const float*)d_in[13];
    const float* t1_bv  = (const float*)d_in[14];
    const float* t1_ws  = (const float*)d_in[15];
    const float* t1_bs  = (const float*)d_in[16];
    const float* t2_wq  = (const float*)d_in[17];
    const float* t2_bq  = (const float*)d_in[18];
    const float* t2_wk  = (const float*)d_in[19];
    const float* t2_bk  = (const float*)d_in[20];
    const float* t2_wv  = (const float*)d_in[21];
    const float* t2_bv  = (const float*)d_in[22];
    const float* t2_wsk = (const float*)d_in[23];
    const float* t2_bs  = (const float*)d_in[24];
    const float* p1_w   = (const float*)d_in[25];
    const float* p1_b   = (const float*)d_in[26];
    const float* p2_w   = (const float*)d_in[27];
    const float* p2_b   = (const float*)d_in[28];
    float* out = (float*)d_out;

    // workspace layout
    char* ws = (char*)d_ws;
    int* off     = (int*)ws;            // NN+1
    int* cursor  = off + (NN + 1);      // NN
    int* csr_src = cursor + NN;         // EE
    size_t ib = ((sizeof(int) * ((size_t)(NN + 1) + NN + EE)) + 255) & ~(size_t)255;
    float* fb   = (float*)(ws + ib);
    float* mean = fb;                         // NN*128  (later: t1 spans mean+h1)
    float* h1   = mean + (size_t)NN * 128;    // NN*128
    float* h2   = h1 + (size_t)NN * 128;      // NN*256  (later reused as h4)
    float* q    = h2 + (size_t)NN * 256;      // NN*256  (later: p1out spans q+k)
    float* kb   = q + (size_t)NN * 256;       // NN*256
    float* vb   = kb + (size_t)NN * 256;      // NN*256  (later reused as hfin)
    float* t1   = mean;    // NN*256 spanning mean+h1
    float* h4   = h2;
    float* p1o  = q;       // NN*512 spanning q+kb
    float* hfin = vb;      // NN*128

    const int* src = ei;
    const int* dst = ei + EE;

    // CSR build
    hipMemsetAsync(cursor, 0, sizeof(int) * NN, stream);
    count_kernel<<<(EE + 255) / 256, 256, 0, stream>>>(dst, cursor, EE);
    scan_kernel<<<1, 1024, 0, stream>>>(cursor, off, NN);
    fill_kernel<<<(EE + 255) / 256, 256, 0, stream>>>(src, dst, cursor, csr_src, EE);

    // SAGE 1: h1 = relu(mean(x) @ wl + bl + x @ wr)
    mean_kernel<<<NN, 128, 0, stream>>>(x, off, csr_src, mean, 128);
    launch_gemm<0>(mean, s1_wl, s1_bl, h1, NN, 128, 128, stream);
    launch_gemm<1>(x, s1_wr, nullptr, h1, NN, 128, 128, stream);

    // SAGE 2: h2 = relu(mean(h1) @ wl + bl + h1 @ wr)
    mean_kernel<<<NN, 128, 0, stream>>>(h1, off, csr_src, mean, 128);
    launch_gemm<0>(mean, s2_wl, s2_bl, h2, NN, 128, 256, stream);
    launch_gemm<1>(h1, s2_wr, nullptr, h2, NN, 128, 256, stream);

    // TransformerConv 1
    launch_gemm<0>(h2, t1_wq, t1_bq, q, NN, 256, 256, stream);
    launch_gemm<0>(h2, t1_wk, t1_bk, kb, NN, 256, 256, stream);
    launch_gemm<0>(h2, t1_wv, t1_bv, vb, NN, 256, 256, stream);
    launch_gemm<0>(h2, t1_ws, t1_bs, t1, NN, 256, 256, stream);
    attn_kernel<<<NN, 256, 0, stream>>>(q, kb, vb, off, csr_src, t1);

    // TransformerConv 2
    launch_gemm<0>(t1, t2_wq, t2_bq, q, NN, 256, 256, stream);
    launch_gemm<0>(t1, t2_wk, t2_bk, kb, NN, 256, 256, stream);
    launch_gemm<0>(t1, t2_wv, t2_bv, vb, NN, 256, 256, stream);
    launch_gemm<0>(t1, t2_wsk, t2_bs, h4, NN, 256, 256, stream);
    attn_kernel<<<NN, 256, 0, stream>>>(q, kb, vb, off, csr_src, h4);

    // proj MLP
    launch_gemm<2>(h4, p1_w, p1_b, p1o, NN, 256, 512, stream);
    launch_gemm<3>(p1o, p2_w, p2_b, hfin, NN, 512, 128, stream);

    // global max pool
    hipMemsetAsync(out, 0, sizeof(float) * (size_t)out_size, stream);
    pool_kernel<<<(NN + 63) / 64, 128, 0, stream>>>(hfin, batch, out);
}

// Round 2
// 735.454 us; speedup vs baseline: 1.7920x; 1.7920x over previous
//
#include <hip/hip_runtime.h>
#include <hip/hip_bf16.h>
#include <math.h>

#define NN 20000
#define EE 320000
#define GG 64

typedef __hip_bfloat16 bf16;
typedef __attribute__((ext_vector_type(8))) short short8;
typedef __attribute__((ext_vector_type(4))) float f32x4;

// ---------------------------------------------------------------------------
// async global->LDS 16B copy (wave-uniform base + lane*16 pattern)
// ---------------------------------------------------------------------------
__device__ __forceinline__ void load_lds16(const void* g, void* l) {
    __builtin_amdgcn_global_load_lds(
        (const __attribute__((address_space(1))) unsigned int*)g,
        (__attribute__((address_space(3))) unsigned int*)l, 16, 0, 0);
}

// ---------------------------------------------------------------------------
// CSR construction: count -> scan -> fill
// ---------------------------------------------------------------------------
__global__ __launch_bounds__(256) void count_kernel(const int* __restrict__ dst,
                                                    int* __restrict__ cnt, int E) {
    int e = blockIdx.x * 256 + threadIdx.x;
    if (e < E) atomicAdd(&cnt[dst[e]], 1);
}

__global__ __launch_bounds__(1024) void scan_kernel(int* __restrict__ cnt,
                                                    int* __restrict__ off, int n) {
    __shared__ int buf[1024];
    __shared__ int carry_s;
    int tid = threadIdx.x;
    if (tid == 0) { carry_s = 0; off[0] = 0; }
    __syncthreads();
    for (int base = 0; base < n; base += 1024) {
        int idx = base + tid;
        int val = (idx < n) ? cnt[idx] : 0;
        buf[tid] = val;
        __syncthreads();
        int x = val;
        for (int s = 1; s < 1024; s <<= 1) {
            int y = (tid >= s) ? buf[tid - s] : 0;
            __syncthreads();
            x += y;
            buf[tid] = x;
            __syncthreads();
        }
        int carry = carry_s;
        if (idx < n) {
            off[idx + 1] = carry + x;
            cnt[idx] = carry + x - val;
        }
        __syncthreads();
        if (tid == 1023) carry_s = carry + x;
        __syncthreads();
    }
}

__global__ __launch_bounds__(256) void fill_kernel(const int* __restrict__ src,
                                                   const int* __restrict__ dst,
                                                   int* __restrict__ cursor,
                                                   int* __restrict__ csr_src, int E) {
    int e = blockIdx.x * 256 + threadIdx.x;
    if (e < E) {
        int p = atomicAdd(&cursor[dst[e]], 1);
        csr_src[p] = src[e];
    }
}

// ---------------------------------------------------------------------------
// converts
// ---------------------------------------------------------------------------
__global__ __launch_bounds__(256) void conv_kernel(const float* __restrict__ in,
                                                   bf16* __restrict__ out, int n) {
    int i = blockIdx.x * 256 + threadIdx.x;
    if (i < n) out[i] = __float2bfloat16(in[i]);
}

// Wt[n*K + k] = bf16(W[k*N + n])   (transpose + convert; tiny matrices)
__global__ __launch_bounds__(256) void convt_kernel(const float* __restrict__ W,
                                                    bf16* __restrict__ Wt, int K, int N) {
    int i = blockIdx.x * 256 + threadIdx.x;
    if (i < K * N) {
        int n = i / K, k = i - n * K;
        Wt[i] = __float2bfloat16(W[(size_t)k * N + n]);
    }
}

// ---------------------------------------------------------------------------
// Mean aggregation over CSR neighbors (bf16 in/out, fp32 accum). F=128.
// ---------------------------------------------------------------------------
__global__ __launch_bounds__(128) void mean_kernel(const bf16* __restrict__ x,
                                                   const int* __restrict__ off,
                                                   const int* __restrict__ csr_src,
                                                   bf16* __restrict__ mean) {
    int i = blockIdx.x;
    int f = threadIdx.x;
    int e0 = off[i], e1 = off[i + 1];
    float s = 0.f;
    for (int e = e0; e < e1; e++) s += __bfloat162float(x[(size_t)csr_src[e] * 128 + f]);
    int deg = e1 - e0;
    mean[(size_t)i * 128 + f] = __float2bfloat16((deg > 0) ? s / (float)deg : 0.f);
}

// ---------------------------------------------------------------------------
// bf16 MFMA GEMM: C[M,N] = A[M,K] @ Wt[N,K]^T, fused epilogue.
// MODE 0: C = A@W + bias            (store bf16)
// MODE 1: C = relu(C + A@W)         (C read/written bf16, no bias)
// MODE 2: C = relu(A@W + bias)      (store bf16)
// MODE 3: C = sigmoid(A@W + bias)   (store fp32)
// 128x128 tile, 256 threads (4 waves, 2x2 of 64x64), BK=32, 16x16x32 MFMA.
// Requires N%128==0, K%32==0. M tail: loads clamped, stores guarded.
// ---------------------------------------------------------------------------
template <int MODE>
__global__ __launch_bounds__(256, 2) void gemm_kernel(const bf16* __restrict__ A,
                                                      const bf16* __restrict__ Wt,
                                                      const float* __restrict__ bias,
                                                      void* __restrict__ Cv,
                                                      int M, int K, int N) {
    __shared__ short As[128 * 32];  // [row m][k] 8 KB
    __shared__ short Bs[128 * 32];  // [row n][k] 8 KB
    int t = threadIdx.x;
    int lane = t & 63;
    int wave = t >> 6;
    int wm = (wave >> 1) * 64, wn = (wave & 1) * 64;
    int bm = blockIdx.y * 128, bn = blockIdx.x * 128;
    int quad = lane >> 4, l16 = lane & 15;
    int srow = t >> 2;          // staging row 0..63 (per round)
    int scol = (t & 3) * 8;     // staging k-offset (8 bf16 = 16 B)

    f32x4 acc[4][4];
    f32x4 zero = {0.f, 0.f, 0.f, 0.f};
    #pragma unroll
    for (int i = 0; i < 4; i++)
        #pragma unroll
        for (int j = 0; j < 4; j++) acc[i][j] = zero;

    for (int kk = 0; kk < K; kk += 32) {
        #pragma unroll
        for (int r = 0; r < 2; r++) {
            int row = r * 64 + srow;
            int gm = bm + row; gm = (gm < M) ? gm : (M - 1);
            load_lds16(A + (size_t)gm * K + kk + scol, &As[row * 32 + scol]);
            int gn = bn + row;
            load_lds16(Wt + (size_t)gn * K + kk + scol, &Bs[row * 32 + scol]);
        }
        __syncthreads();
        short8 af[4], bfr[4];
        #pragma unroll
        for (int i = 0; i < 4; i++) {
            af[i]  = *(const short8*)&As[(wm + i * 16 + l16) * 32 + quad * 8];
            bfr[i] = *(const short8*)&Bs[(wn + i * 16 + l16) * 32 + quad * 8];
        }
        #pragma unroll
        for (int i = 0; i < 4; i++)
            #pragma unroll
            for (int j = 0; j < 4; j++)
                acc[i][j] = __builtin_amdgcn_mfma_f32_16x16x32_bf16(af[i], bfr[j], acc[i][j], 0, 0, 0);
        __syncthreads();
    }

    // epilogue: C/D layout col=lane&15, row=quad*4+reg  [m89/m91-verified]
    #pragma unroll
    for (int i = 0; i < 4; i++) {
        int gm0 = bm + wm + i * 16 + quad * 4;
        #pragma unroll
        for (int j = 0; j < 4; j++) {
            int gn = bn + wn + j * 16 + l16;
            #pragma unroll
            for (int r = 0; r < 4; r++) {
                int gm = gm0 + r;
                if (gm >= M) continue;
                float v = acc[i][j][r];
                if (MODE == 0 || MODE == 2 || MODE == 3) v += bias[gn];
                if (MODE == 1) v += __bfloat162float(((const bf16*)Cv)[(size_t)gm * N + gn]);
                if (MODE == 1 || MODE == 2) v = fmaxf(v, 0.f);
                if (MODE == 3) {
                    v = 1.f / (1.f + expf(-v));
                    ((float*)Cv)[(size_t)gm * N + gn] = v;
                } else {
                    ((bf16*)Cv)[(size_t)gm * N + gn] = __float2bfloat16(v);
                }
            }
        }
    }
}

template <int MODE>
static void launch_gemm(const bf16* A, const bf16* Wt, const float* bias, void* C,
                        int M, int K, int N, hipStream_t st) {
    dim3 grid(N / 128, (M + 127) / 128);
    hipLaunchKernelGGL((gemm_kernel<MODE>), grid, dim3(256), 0, st, A, Wt, bias, C, M, K, N);
}

// ---------------------------------------------------------------------------
// TransformerConv attention over fused qkvs buffer (stride 1024 per node:
// [q(256) k(256) v(256) skip(256)]). block=256 = 8 heads x 32 dims.
// out[i,tid] = relu(skip + softmax-weighted sum of v over neighbors), bf16.
// ---------------------------------------------------------------------------
__global__ __launch_bounds__(256) void attn_kernel(const bf16* __restrict__ qkvs,
                                                   const int* __restrict__ off,
                                                   const int* __restrict__ csr_src,
                                                   bf16* __restrict__ out) {
    int i = blockIdx.x;
    int tid = threadIdx.x;  // h = tid>>5, d = tid&31
    const bf16* base_i = qkvs + (size_t)i * 1024;
    float qv = __bfloat162float(base_i[tid]);
    int e0 = off[i], e1 = off[i + 1];
    float m = -INFINITY, l = 0.f, acc = 0.f;
    for (int e = e0; e < e1; e++) {
        int s = csr_src[e];
        const bf16* base_s = qkvs + (size_t)s * 1024;
        float kv = __bfloat162float(base_s[256 + tid]);
        float prod = qv * kv;
        #pragma unroll
        for (int w = 16; w >= 1; w >>= 1) prod += __shfl_xor(prod, w, 32);
        float logit = prod * 0.17677669529663687f;  // 1/sqrt(32)
        float mn = fmaxf(m, logit);
        float esc = expf(m - mn);
        float p = expf(logit - mn);
        float vv = __bfloat162float(base_s[512 + tid]);
        l = l * esc + p;
        acc = acc * esc + p * vv;
        m = mn;
    }
    float res = (l > 0.f) ? acc / l : 0.f;
    float val = res + __bfloat162float(base_i[768 + tid]);
    out[(size_t)i * 256 + tid] = __float2bfloat16(fmaxf(val, 0.f));
}

// ---------------------------------------------------------------------------
// Global max pool over sorted batch (hfin fp32, positive sigmoid outputs).
// ---------------------------------------------------------------------------
__global__ __launch_bounds__(128) void pool_kernel(const float* __restrict__ hfin,
                                                   const int* __restrict__ batch,
                                                   float* __restrict__ out) {
    int f = threadIdx.x;
    int i0 = blockIdx.x * 64;
    int i1 = i0 + 64;
    if (i1 > NN) i1 = NN;
    int cur_g = -1;
    float cur_max = 0.f;
    for (int i = i0; i < i1; i++) {
        int g = batch[i];
        float val = hfin[(size_t)i * 128 + f];
        if (g != cur_g) {
            if (cur_g >= 0) atomicMax((int*)&out[cur_g * 128 + f], __float_as_int(cur_max));
            cur_g = g;
            cur_max = val;
        } else {
            cur_max = fmaxf(cur_max, val);
        }
    }
    if (cur_g >= 0) atomicMax((int*)&out[cur_g * 128 + f], __float_as_int(cur_max));
}

// ---------------------------------------------------------------------------
extern "C" void kernel_launch(void* const* d_in, const int* in_sizes, int n_in,
                              void* d_out, int out_size, void* d_ws, size_t ws_size,
                              hipStream_t stream) {
    const float* x      = (const float*)d_in[0];
    const int*   ei     = (const int*)d_in[1];
    const int*   batch  = (const int*)d_in[2];
    const float* s1_wl  = (const float*)d_in[3];
    const float* s1_bl  = (const float*)d_in[4];
    const float* s1_wr  = (const float*)d_in[5];
    const float* s2_wl  = (const float*)d_in[6];
    const float* s2_bl  = (const float*)d_in[7];
    const float* s2_wr  = (const float*)d_in[8];
    const float* t1_wq  = (const float*)d_in[9];
    const float* t1_bq  = (const float*)d_in[10];
    const float* t1_wk  = (const float*)d_in[11];
    const float* t1_bk  = (const float*)d_in[12];
    const float* t1_wv  = (const float*)d_in[13];
    const float* t1_bv  = (const float*)d_in[14];
    const float* t1_ws  = (const float*)d_in[15];
    const float* t1_bs  = (const float*)d_in[16];
    const float* t2_wq  = (const float*)d_in[17];
    const float* t2_bq  = (const float*)d_in[18];
    const float* t2_wk  = (const float*)d_in[19];
    const float* t2_bk  = (const float*)d_in[20];
    const float* t2_wv  = (const float*)d_in[21];
    const float* t2_bv  = (const float*)d_in[22];
    const float* t2_wsk = (const float*)d_in[23];
    const float* t2_bs  = (const float*)d_in[24];
    const float* p1_w   = (const float*)d_in[25];
    const float* p1_b   = (const float*)d_in[26];
    const float* p2_w   = (const float*)d_in[27];
    const float* p2_b   = (const float*)d_in[28];
    float* out = (float*)d_out;

    // ---- workspace layout ----
    char* ws = (char*)d_ws;
    size_t o = 0;
    auto alloc = [&](size_t bytes) { char* p = ws + o; o += (bytes + 255) & ~(size_t)255; return p; };
    int* off     = (int*)alloc(sizeof(int) * (NN + 1));
    int* cursor  = (int*)alloc(sizeof(int) * NN);
    int* csr_src = (int*)alloc(sizeof(int) * EE);
    bf16* wl1t = (bf16*)alloc(2 * 128 * 128);
    bf16* wr1t = (bf16*)alloc(2 * 128 * 128);
    bf16* wl2t = (bf16*)alloc(2 * 128 * 256);
    bf16* wr2t = (bf16*)alloc(2 * 128 * 256);
    bf16* qw1  = (bf16*)alloc(2 * 1024 * 256);
    bf16* qw2  = (bf16*)alloc(2 * 1024 * 256);
    bf16* p1t  = (bf16*)alloc(2 * 512 * 256);
    bf16* p2t  = (bf16*)alloc(2 * 128 * 512);
    float* qb1 = (float*)alloc(4 * 1024);
    float* qb2 = (float*)alloc(4 * 1024);
    bf16* h1   = (bf16*)alloc(2 * (size_t)NN * 128);
    bf16* h2   = (bf16*)alloc(2 * (size_t)NN * 256);   // also h4 (attn2 out)
    bf16* t1   = (bf16*)alloc(2 * (size_t)NN * 256);   // also hfin (fp32 NN*128)
    bf16* Q    = (bf16*)alloc(2 * (size_t)NN * 1024);  // qkvs / p1o; early: xb, meanb
    bf16* xb    = Q;                                   // NN*128 (dead before qkvs1)
    bf16* meanb = Q + (size_t)NN * 128;                // NN*128 (dead before qkvs1)
    bf16* h4    = h2;
    float* hfin = (float*)t1;

    const int* src = ei;
    const int* dst = ei + EE;

    // ---- weight/bias/x converts ----
    auto convt = [&](const float* W, bf16* Wt, int K, int N) {
        int n = K * N;
        convt_kernel<<<(n + 255) / 256, 256, 0, stream>>>(W, Wt, K, N);
    };
    conv_kernel<<<(NN * 128 + 255) / 256, 256, 0, stream>>>(x, xb, NN * 128);
    convt(s1_wl, wl1t, 128, 128);
    convt(s1_wr, wr1t, 128, 128);
    convt(s2_wl, wl2t, 128, 256);
    convt(s2_wr, wr2t, 128, 256);
    convt(t1_wq, qw1 + 0 * 256 * 256, 256, 256);
    convt(t1_wk, qw1 + 1 * 256 * 256, 256, 256);
    convt(t1_wv, qw1 + 2 * 256 * 256, 256, 256);
    convt(t1_ws, qw1 + 3 * 256 * 256, 256, 256);
    convt(t2_wq, qw2 + 0 * 256 * 256, 256, 256);
    convt(t2_wk, qw2 + 1 * 256 * 256, 256, 256);
    convt(t2_wv, qw2 + 2 * 256 * 256, 256, 256);
    convt(t2_wsk, qw2 + 3 * 256 * 256, 256, 256);
    convt(p1_w, p1t, 256, 512);
    convt(p2_w, p2t, 512, 128);
    hipMemcpyAsync(qb1 + 0,   t1_bq, 1024, hipMemcpyDeviceToDevice, stream);
    hipMemcpyAsync(qb1 + 256, t1_bk, 1024, hipMemcpyDeviceToDevice, stream);
    hipMemcpyAsync(qb1 + 512, t1_bv, 1024, hipMemcpyDeviceToDevice, stream);
    hipMemcpyAsync(qb1 + 768, t1_bs, 1024, hipMemcpyDeviceToDevice, stream);
    hipMemcpyAsync(qb2 + 0,   t2_bq, 1024, hipMemcpyDeviceToDevice, stream);
    hipMemcpyAsync(qb2 + 256, t2_bk, 1024, hipMemcpyDeviceToDevice, stream);
    hipMemcpyAsync(qb2 + 512, t2_bv, 1024, hipMemcpyDeviceToDevice, stream);
    hipMemcpyAsync(qb2 + 768, t2_bs, 1024, hipMemcpyDeviceToDevice, stream);

    // ---- CSR build ----
    hipMemsetAsync(cursor, 0, sizeof(int) * NN, stream);
    count_kernel<<<(EE + 255) / 256, 256, 0, stream>>>(dst, cursor, EE);
    scan_kernel<<<1, 1024, 0, stream>>>(cursor, off, NN);
    fill_kernel<<<(EE + 255) / 256, 256, 0, stream>>>(src, dst, cursor, csr_src, EE);

    // ---- SAGE 1 ----
    mean_kernel<<<NN, 128, 0, stream>>>(xb, off, csr_src, meanb);
    launch_gemm<0>(meanb, wl1t, s1_bl, h1, NN, 128, 128, stream);
    launch_gemm<1>(xb, wr1t, nullptr, h1, NN, 128, 128, stream);

    // ---- SAGE 2 ----
    mean_kernel<<<NN, 128, 0, stream>>>(h1, off, csr_src, meanb);
    launch_gemm<0>(meanb, wl2t, s2_bl, h2, NN, 128, 256, stream);
    launch_gemm<1>(h1, wr2t, nullptr, h2, NN, 128, 256, stream);

    // ---- TransformerConv 1 (fused qkvs GEMM + attention) ----
    launch_gemm<0>(h2, qw1, qb1, Q, NN, 256, 1024, stream);
    attn_kernel<<<NN, 256, 0, stream>>>(Q, off, csr_src, t1);

    // ---- TransformerConv 2 ----
    launch_gemm<0>(t1, qw2, qb2, Q, NN, 256, 1024, stream);
    attn_kernel<<<NN, 256, 0, stream>>>(Q, off, csr_src, h4);

    // ---- proj MLP ----
    launch_gemm<2>(h4, p1t, p1_b, Q, NN, 256, 512, stream);
    launch_gemm<3>(Q, p2t, p2_b, hfin, NN, 512, 128, stream);

    // ---- global max pool ----
    hipMemsetAsync(out, 0, sizeof(float) * (size_t)out_size, stream);
    pool_kernel<<<(NN + 63) / 64, 128, 0, stream>>>(hfin, batch, out);
}

// Round 3
// 581.486 us; speedup vs baseline: 2.2665x; 1.2648x over previous
//
#include <hip/hip_runtime.h>
#include <hip/hip_bf16.h>
#include <math.h>

#define NN 20000
#define EE 320000
#define GG 64
#define CH 16   // attention chunk size (edges)

typedef __hip_bfloat16 bf16;
typedef __attribute__((ext_vector_type(8))) short short8;
typedef __attribute__((ext_vector_type(4))) float f32x4;
typedef unsigned int uint;
typedef unsigned short ushort;

__device__ __forceinline__ float bfr2f(ushort u) {
    union { uint i; float f; } c; c.i = ((uint)u) << 16; return c.f;
}
__device__ __forceinline__ ushort f2bfr(float f) {
    bf16 h = __float2bfloat16(f);
    return *(ushort*)&h;
}

// ---------------------------------------------------------------------------
// async global->LDS 16B copy
// ---------------------------------------------------------------------------
__device__ __forceinline__ void load_lds16(const void* g, void* l) {
    __builtin_amdgcn_global_load_lds(
        (const __attribute__((address_space(1))) unsigned int*)g,
        (__attribute__((address_space(3))) unsigned int*)l, 16, 0, 0);
}

// ---------------------------------------------------------------------------
// CSR construction
// ---------------------------------------------------------------------------
__global__ __launch_bounds__(256) void count_kernel(const int* __restrict__ dst,
                                                    int* __restrict__ cnt, int E) {
    int e = blockIdx.x * 256 + threadIdx.x;
    if (e < E) atomicAdd(&cnt[dst[e]], 1);
}

__global__ __launch_bounds__(1024) void scan_kernel(int* __restrict__ cnt,
                                                    int* __restrict__ off, int n) {
    __shared__ int buf[1024];
    __shared__ int carry_s;
    int tid = threadIdx.x;
    if (tid == 0) { carry_s = 0; off[0] = 0; }
    __syncthreads();
    for (int base = 0; base < n; base += 1024) {
        int idx = base + tid;
        int val = (idx < n) ? cnt[idx] : 0;
        buf[tid] = val;
        __syncthreads();
        int x = val;
        for (int s = 1; s < 1024; s <<= 1) {
            int y = (tid >= s) ? buf[tid - s] : 0;
            __syncthreads();
            x += y;
            buf[tid] = x;
            __syncthreads();
        }
        int carry = carry_s;
        if (idx < n) {
            off[idx + 1] = carry + x;
            cnt[idx] = carry + x - val;
        }
        __syncthreads();
        if (tid == 1023) carry_s = carry + x;
        __syncthreads();
    }
}

__global__ __launch_bounds__(256) void fill_kernel(const int* __restrict__ src,
                                                   const int* __restrict__ dst,
                                                   int* __restrict__ cursor,
                                                   int* __restrict__ csr_src, int E) {
    int e = blockIdx.x * 256 + threadIdx.x;
    if (e < E) {
        int p = atomicAdd(&cursor[dst[e]], 1);
        csr_src[p] = src[e];
    }
}

// ---------------------------------------------------------------------------
// converts
// ---------------------------------------------------------------------------
// fp32 [rows,128] -> bf16 strided rows
__global__ __launch_bounds__(256) void conv2_kernel(const float* __restrict__ in,
                                                    bf16* __restrict__ out, int n, int ostride) {
    int i = blockIdx.x * 256 + threadIdx.x;
    if (i < n) {
        int r = i >> 7, c = i & 127;
        out[(size_t)r * ostride + c] = __float2bfloat16(in[i]);
    }
}

// W [Kw,Nw] fp32 -> Wt rows n: Wt[n*Ktot + koff + k] = bf16(W[k*Nw + n])
__global__ __launch_bounds__(256) void convt2_kernel(const float* __restrict__ W,
                                                     bf16* __restrict__ Wt,
                                                     int Kw, int Nw, int Ktot, int koff) {
    int i = blockIdx.x * 256 + threadIdx.x;
    if (i < Kw * Nw) {
        int n = i / Kw, k = i - n * Kw;
        Wt[(size_t)n * Ktot + koff + k] = __float2bfloat16(W[(size_t)k * Nw + n]);
    }
}

// ---------------------------------------------------------------------------
// Mean aggregation: 4 nodes/block, 1 wave/node, bf16x2 per lane (128 dims).
// ---------------------------------------------------------------------------
__global__ __launch_bounds__(256) void mean2_kernel(const bf16* __restrict__ x, int xstride,
                                                    const int* __restrict__ off,
                                                    const int* __restrict__ csr_src,
                                                    bf16* __restrict__ outp, int ostride) {
    int node = blockIdx.x * 4 + (threadIdx.x >> 6);
    int lane = threadIdx.x & 63;
    int e0 = off[node], e1 = off[node + 1];
    float s0 = 0.f, s1 = 0.f;
    int e = e0;
    for (; e + 1 < e1; e += 2) {
        int sa = csr_src[e], sb = csr_src[e + 1];
        uint a = *(const uint*)(x + (size_t)sa * xstride + lane * 2);
        uint b = *(const uint*)(x + (size_t)sb * xstride + lane * 2);
        union { uint i; float f; } c0, c1, c2, c3;
        c0.i = a << 16; c1.i = a & 0xffff0000u;
        c2.i = b << 16; c3.i = b & 0xffff0000u;
        s0 += c0.f + c2.f;
        s1 += c1.f + c3.f;
    }
    if (e < e1) {
        int sa = csr_src[e];
        uint a = *(const uint*)(x + (size_t)sa * xstride + lane * 2);
        union { uint i; float f; } c0, c1;
        c0.i = a << 16; c1.i = a & 0xffff0000u;
        s0 += c0.f; s1 += c1.f;
    }
    int deg = e1 - e0;
    float inv = (deg > 0) ? 1.f / (float)deg : 0.f;
    uint r = ((uint)f2bfr(s1 * inv) << 16) | (uint)f2bfr(s0 * inv);
    *(uint*)(outp + (size_t)node * ostride + lane * 2) = r;
}

// ---------------------------------------------------------------------------
// bf16 MFMA GEMM: C[M,N] = A[M,K] @ Wt[N,K]^T, fused epilogue.
// MODE 0: C = A@W + bias            (store bf16)
// MODE 2: C = relu(A@W + bias)      (store bf16)
// MODE 3: C = sigmoid(A@W + bias)   (store fp32)
// 128x128 tile, 256 threads, BK=32, 16x16x32 MFMA. C row stride = cstride.
// ---------------------------------------------------------------------------
template <int MODE>
__global__ __launch_bounds__(256, 2) void gemm_kernel(const bf16* __restrict__ A,
                                                      const bf16* __restrict__ Wt,
                                                      const float* __restrict__ bias,
                                                      void* __restrict__ Cv,
                                                      int M, int K, int N, int cstride) {
    __shared__ short As[128 * 32];
    __shared__ short Bs[128 * 32];
    int t = threadIdx.x;
    int lane = t & 63;
    int wave = t >> 6;
    int wm = (wave >> 1) * 64, wn = (wave & 1) * 64;
    int bm = blockIdx.y * 128, bn = blockIdx.x * 128;
    int quad = lane >> 4, l16 = lane & 15;
    int srow = t >> 2;
    int scol = (t & 3) * 8;

    f32x4 acc[4][4];
    f32x4 zero = {0.f, 0.f, 0.f, 0.f};
    #pragma unroll
    for (int i = 0; i < 4; i++)
        #pragma unroll
        for (int j = 0; j < 4; j++) acc[i][j] = zero;

    for (int kk = 0; kk < K; kk += 32) {
        #pragma unroll
        for (int r = 0; r < 2; r++) {
            int row = r * 64 + srow;
            int gm = bm + row; gm = (gm < M) ? gm : (M - 1);
            load_lds16(A + (size_t)gm * K + kk + scol, &As[row * 32 + scol]);
            int gn = bn + row;
            load_lds16(Wt + (size_t)gn * K + kk + scol, &Bs[row * 32 + scol]);
        }
        __syncthreads();
        short8 af[4], bfr[4];
        #pragma unroll
        for (int i = 0; i < 4; i++) {
            af[i]  = *(const short8*)&As[(wm + i * 16 + l16) * 32 + quad * 8];
            bfr[i] = *(const short8*)&Bs[(wn + i * 16 + l16) * 32 + quad * 8];
        }
        #pragma unroll
        for (int i = 0; i < 4; i++)
            #pragma unroll
            for (int j = 0; j < 4; j++)
                acc[i][j] = __builtin_amdgcn_mfma_f32_16x16x32_bf16(af[i], bfr[j], acc[i][j], 0, 0, 0);
        __syncthreads();
    }

    #pragma unroll
    for (int i = 0; i < 4; i++) {
        int gm0 = bm + wm + i * 16 + quad * 4;
        #pragma unroll
        for (int j = 0; j < 4; j++) {
            int gn = bn + wn + j * 16 + l16;
            #pragma unroll
            for (int r = 0; r < 4; r++) {
                int gm = gm0 + r;
                if (gm >= M) continue;
                float v = acc[i][j][r] + bias[gn];
                if (MODE == 2) v = fmaxf(v, 0.f);
                if (MODE == 3) {
                    v = 1.f / (1.f + expf(-v));
                    ((float*)Cv)[(size_t)gm * cstride + gn] = v;
                } else {
                    ((bf16*)Cv)[(size_t)gm * cstride + gn] = __float2bfloat16(v);
                }
            }
        }
    }
}

template <int MODE>
static void launch_gemm(const bf16* A, const bf16* Wt, const float* bias, void* C,
                        int M, int K, int N, int cstride, hipStream_t st) {
    dim3 grid(N / 128, (M + 127) / 128);
    hipLaunchKernelGGL((gemm_kernel<MODE>), grid, dim3(256), 0, st, A, Wt, bias, C, M, K, N, cstride);
}

// ---------------------------------------------------------------------------
// TransformerConv attention v2: 3-phase chunked online softmax.
// qkvs row stride 1024: [q(256) k(256) v(256) skip(256)]. Block = 1 node.
// Phase A: lane=(e,h,half) 16-dim dot; B: per-head softmax merge (exp once
// per edge-head); C: thread-per-dim weighted V, unrolled x2.
// ---------------------------------------------------------------------------
__global__ __launch_bounds__(256) void attn2_kernel(const bf16* __restrict__ qkvs,
                                                    const int* __restrict__ off,
                                                    const int* __restrict__ csr_src,
                                                    bf16* __restrict__ out, int ostride) {
    __shared__ float lg[CH][9];
    __shared__ float pp[CH][9];
    __shared__ int srcs[CH];
    int i = blockIdx.x;
    int tid = threadIdx.x;
    // phase A mapping
    int ea = tid >> 4, ha = (tid >> 1) & 7, half = tid & 1;
    // phase B/C mapping
    int hc = tid >> 5, dc = tid & 31;

    // q fragment (16 dims) in registers
    float qf[16];
    {
        const short8* qp = (const short8*)(qkvs + (size_t)i * 1024 + ha * 32 + half * 16);
        #pragma unroll
        for (int c = 0; c < 2; c++) {
            short8 v = qp[c];
            #pragma unroll
            for (int j = 0; j < 8; j++) qf[c * 8 + j] = bfr2f((ushort)v[j]);
        }
    }

    int e0 = off[i], e1 = off[i + 1];
    float m = -INFINITY, l = 0.f, acc = 0.f;
    for (int base = e0; base < e1; base += CH) {
        int cnt = min(CH, e1 - base);
        // ---- A: logits ----
        int s = 0;
        if (ea < cnt) s = csr_src[base + ea];
        if ((tid & 15) == 0) srcs[ea] = s;
        if (ea < cnt) {
            const short8* kp = (const short8*)(qkvs + (size_t)s * 1024 + 256 + ha * 32 + half * 16);
            float d = 0.f;
            #pragma unroll
            for (int c = 0; c < 2; c++) {
                short8 kv = kp[c];
                #pragma unroll
                for (int j = 0; j < 8; j++) d += qf[c * 8 + j] * bfr2f((ushort)kv[j]);
            }
            d += __shfl_xor(d, 1);
            if (half == 0) lg[ea][ha] = d * 0.17677669529663687f;  // 1/sqrt(32)
        }
        __syncthreads();
        // ---- B: softmax merge (per head, 32 lanes) ----
        float lo = (dc < cnt) ? lg[dc][hc] : -INFINITY;
        float cm = lo;
        #pragma unroll
        for (int w = 16; w >= 1; w >>= 1) cm = fmaxf(cm, __shfl_xor(cm, w, 32));
        float mn = fmaxf(m, cm);
        float alpha = __expf(m - mn);
        float p = (dc < cnt) ? __expf(lo - mn) : 0.f;
        if (dc < CH) pp[dc][hc] = p;
        float ps = p;
        #pragma unroll
        for (int w = 16; w >= 1; w >>= 1) ps += __shfl_xor(ps, w, 32);
        l = l * alpha + ps;
        m = mn;
        __syncthreads();
        // ---- C: weighted V accumulation (thread = dim) ----
        acc *= alpha;
        for (int e = 0; e < cnt; e += 2) {
            float p0 = pp[e][hc];
            float p1 = pp[e + 1][hc];        // zero-padded when e+1 == cnt
            int s0 = srcs[e];
            int s1 = srcs[e + 1];
            float v0 = bfr2f(*(const ushort*)(qkvs + (size_t)s0 * 1024 + 512 + tid));
            float v1 = bfr2f(*(const ushort*)(qkvs + (size_t)s1 * 1024 + 512 + tid));
            acc += p0 * v0 + p1 * v1;
        }
        __syncthreads();
    }
    float res = (l > 0.f) ? acc / l : 0.f;
    float val = res + bfr2f(*(const ushort*)(qkvs + (size_t)i * 1024 + 768 + tid));
    out[(size_t)i * ostride + tid] = __float2bfloat16(fmaxf(val, 0.f));
}

// ---------------------------------------------------------------------------
// Global max pool over sorted batch.
// ---------------------------------------------------------------------------
__global__ __launch_bounds__(128) void pool_kernel(const float* __restrict__ hfin,
                                                   const int* __restrict__ batch,
                                                   float* __restrict__ out) {
    int f = threadIdx.x;
    int i0 = blockIdx.x * 64;
    int i1 = i0 + 64;
    if (i1 > NN) i1 = NN;
    int cur_g = -1;
    float cur_max = 0.f;
    for (int i = i0; i < i1; i++) {
        int g = batch[i];
        float val = hfin[(size_t)i * 128 + f];
        if (g != cur_g) {
            if (cur_g >= 0) atomicMax((int*)&out[cur_g * 128 + f], __float_as_int(cur_max));
            cur_g = g;
            cur_max = val;
        } else {
            cur_max = fmaxf(cur_max, val);
        }
    }
    if (cur_g >= 0) atomicMax((int*)&out[cur_g * 128 + f], __float_as_int(cur_max));
}

// ---------------------------------------------------------------------------
extern "C" void kernel_launch(void* const* d_in, const int* in_sizes, int n_in,
                              void* d_out, int out_size, void* d_ws, size_t ws_size,
                              hipStream_t stream) {
    const float* x      = (const float*)d_in[0];
    const int*   ei     = (const int*)d_in[1];
    const int*   batch  = (const int*)d_in[2];
    const float* s1_wl  = (const float*)d_in[3];
    const float* s1_bl  = (const float*)d_in[4];
    const float* s1_wr  = (const float*)d_in[5];
    const float* s2_wl  = (const float*)d_in[6];
    const float* s2_bl  = (const float*)d_in[7];
    const float* s2_wr  = (const float*)d_in[8];
    const float* t1_wq  = (const float*)d_in[9];
    const float* t1_bq  = (const float*)d_in[10];
    const float* t1_wk  = (const float*)d_in[11];
    const float* t1_bk  = (const float*)d_in[12];
    const float* t1_wv  = (const float*)d_in[13];
    const float* t1_bv  = (const float*)d_in[14];
    const float* t1_ws  = (const float*)d_in[15];
    const float* t1_bs  = (const float*)d_in[16];
    const float* t2_wq  = (const float*)d_in[17];
    const float* t2_bq  = (const float*)d_in[18];
    const float* t2_wk  = (const float*)d_in[19];
    const float* t2_bk  = (const float*)d_in[20];
    const float* t2_wv  = (const float*)d_in[21];
    const float* t2_bv  = (const float*)d_in[22];
    const float* t2_wsk = (const float*)d_in[23];
    const float* t2_bs  = (const float*)d_in[24];
    const float* p1_w   = (const float*)d_in[25];
    const float* p1_b   = (const float*)d_in[26];
    const float* p2_w   = (const float*)d_in[27];
    const float* p2_b   = (const float*)d_in[28];
    float* out = (float*)d_out;

    // ---- workspace layout ----
    char* ws = (char*)d_ws;
    size_t o = 0;
    auto alloc = [&](size_t bytes) { char* p = ws + o; o += (bytes + 255) & ~(size_t)255; return p; };
    int* off     = (int*)alloc(sizeof(int) * (NN + 1));
    int* cursor  = (int*)alloc(sizeof(int) * NN);
    int* csr_src = (int*)alloc(sizeof(int) * EE);
    bf16* w1cat = (bf16*)alloc(2 * 128 * 256);   // [wr1 ; wl1] K=256, N=128
    bf16* w2cat = (bf16*)alloc(2 * 256 * 256);   // [wr2 ; wl2] K=256, N=256
    bf16* qw1   = (bf16*)alloc(2 * 1024 * 256);
    bf16* qw2   = (bf16*)alloc(2 * 1024 * 256);
    bf16* p1t   = (bf16*)alloc(2 * 512 * 256);
    bf16* p2t   = (bf16*)alloc(2 * 128 * 512);
    float* qb1  = (float*)alloc(4 * 1024);
    float* qb2  = (float*)alloc(4 * 1024);
    bf16* xm1   = (bf16*)alloc(2 * (size_t)NN * 256);   // [x | mean(x)]; later h2/h4
    bf16* xm2   = (bf16*)alloc(2 * (size_t)NN * 256);   // [h1 | mean(h1)]
    bf16* t1b   = (bf16*)alloc(2 * (size_t)NN * 512);   // t1 (stride 256); later p1o (stride 512)
    bf16* Q     = (bf16*)alloc(2 * (size_t)NN * 1024);  // qkvs; later hfin (fp32 NN*128)
    bf16* h2   = xm1;
    bf16* t1   = t1b;
    bf16* h4   = xm1;
    bf16* p1o  = t1b;
    float* hfin = (float*)Q;

    const int* src = ei;
    const int* dst = ei + EE;

    // ---- weight converts ----
    auto convt2 = [&](const float* W, bf16* Wt, int Kw, int Nw, int Ktot, int koff) {
        int n = Kw * Nw;
        convt2_kernel<<<(n + 255) / 256, 256, 0, stream>>>(W, Wt, Kw, Nw, Ktot, koff);
    };
    convt2(s1_wr, w1cat, 128, 128, 256, 0);
    convt2(s1_wl, w1cat, 128, 128, 256, 128);
    convt2(s2_wr, w2cat, 128, 256, 256, 0);
    convt2(s2_wl, w2cat, 128, 256, 256, 128);
    convt2(t1_wq, qw1 + 0 * 256 * 256, 256, 256, 256, 0);
    convt2(t1_wk, qw1 + 1 * 256 * 256, 256, 256, 256, 0);
    convt2(t1_wv, qw1 + 2 * 256 * 256, 256, 256, 256, 0);
    convt2(t1_ws, qw1 + 3 * 256 * 256, 256, 256, 256, 0);
    convt2(t2_wq, qw2 + 0 * 256 * 256, 256, 256, 256, 0);
    convt2(t2_wk, qw2 + 1 * 256 * 256, 256, 256, 256, 0);
    convt2(t2_wv, qw2 + 2 * 256 * 256, 256, 256, 256, 0);
    convt2(t2_wsk, qw2 + 3 * 256 * 256, 256, 256, 256, 0);
    convt2(p1_w, p1t, 256, 512, 256, 0);
    convt2(p2_w, p2t, 512, 128, 512, 0);
    hipMemcpyAsync(qb1 + 0,   t1_bq, 1024, hipMemcpyDeviceToDevice, stream);
    hipMemcpyAsync(qb1 + 256, t1_bk, 1024, hipMemcpyDeviceToDevice, stream);
    hipMemcpyAsync(qb1 + 512, t1_bv, 1024, hipMemcpyDeviceToDevice, stream);
    hipMemcpyAsync(qb1 + 768, t1_bs, 1024, hipMemcpyDeviceToDevice, stream);
    hipMemcpyAsync(qb2 + 0,   t2_bq, 1024, hipMemcpyDeviceToDevice, stream);
    hipMemcpyAsync(qb2 + 256, t2_bk, 1024, hipMemcpyDeviceToDevice, stream);
    hipMemcpyAsync(qb2 + 512, t2_bv, 1024, hipMemcpyDeviceToDevice, stream);
    hipMemcpyAsync(qb2 + 768, t2_bs, 1024, hipMemcpyDeviceToDevice, stream);

    // x -> xm1 first half (stride 256)
    conv2_kernel<<<(NN * 128 + 255) / 256, 256, 0, stream>>>(x, xm1, NN * 128, 256);

    // ---- CSR build ----
    hipMemsetAsync(cursor, 0, sizeof(int) * NN, stream);
    count_kernel<<<(EE + 255) / 256, 256, 0, stream>>>(dst, cursor, EE);
    scan_kernel<<<1, 1024, 0, stream>>>(cursor, off, NN);
    fill_kernel<<<(EE + 255) / 256, 256, 0, stream>>>(src, dst, cursor, csr_src, EE);

    // ---- SAGE 1: h1 = relu([x|mean(x)] @ w1cat + bl) -> xm2 first half ----
    mean2_kernel<<<NN / 4, 256, 0, stream>>>(xm1, 256, off, csr_src, xm1 + 128, 256);
    launch_gemm<2>(xm1, w1cat, s1_bl, xm2, NN, 256, 128, 256, stream);

    // ---- SAGE 2: h2 = relu([h1|mean(h1)] @ w2cat + bl) ----
    mean2_kernel<<<NN / 4, 256, 0, stream>>>(xm2, 256, off, csr_src, xm2 + 128, 256);
    launch_gemm<2>(xm2, w2cat, s2_bl, h2, NN, 256, 256, 256, stream);

    // ---- TransformerConv 1 ----
    launch_gemm<0>(h2, qw1, qb1, Q, NN, 256, 1024, 1024, stream);
    attn2_kernel<<<NN, 256, 0, stream>>>(Q, off, csr_src, t1, 256);

    // ---- TransformerConv 2 ----
    launch_gemm<0>(t1, qw2, qb2, Q, NN, 256, 1024, 1024, stream);
    attn2_kernel<<<NN, 256, 0, stream>>>(Q, off, csr_src, h4, 256);

    // ---- proj MLP ----
    launch_gemm<2>(h4, p1t, p1_b, p1o, NN, 256, 512, 512, stream);
    launch_gemm<3>(p1o, p2t, p2_b, hfin, NN, 512, 128, 128, stream);

    // ---- global max pool ----
    hipMemsetAsync(out, 0, sizeof(float) * (size_t)out_size, stream);
    pool_kernel<<<(NN + 63) / 64, 128, 0, stream>>>(hfin, batch, out);
}

// Round 4
// 492.227 us; speedup vs baseline: 2.6775x; 1.1813x over previous
//
#include <hip/hip_runtime.h>
#include <hip/hip_bf16.h>
#include <math.h>

#define NN 20000
#define EE 320000
#define GG 64
#define CH 16   // attention chunk size (edges)

typedef __hip_bfloat16 bf16;
typedef __attribute__((ext_vector_type(8))) short short8;
typedef __attribute__((ext_vector_type(4))) float f32x4;
typedef unsigned int uint;
typedef unsigned short ushort;

__device__ __forceinline__ float bfr2f(ushort u) {
    union { uint i; float f; } c; c.i = ((uint)u) << 16; return c.f;
}
__device__ __forceinline__ ushort f2bfr(float f) {
    bf16 h = __float2bfloat16(f);
    return *(ushort*)&h;
}

// ---------------------------------------------------------------------------
// async global->LDS 16B copy
// ---------------------------------------------------------------------------
__device__ __forceinline__ void load_lds16(const void* g, void* l) {
    __builtin_amdgcn_global_load_lds(
        (const __attribute__((address_space(1))) unsigned int*)g,
        (__attribute__((address_space(3))) unsigned int*)l, 16, 0, 0);
}

// ---------------------------------------------------------------------------
// CSR construction
// ---------------------------------------------------------------------------
__global__ __launch_bounds__(256) void count_kernel(const int* __restrict__ dst,
                                                    int* __restrict__ cnt, int E) {
    int e = blockIdx.x * 256 + threadIdx.x;
    if (e < E) atomicAdd(&cnt[dst[e]], 1);
}

__global__ __launch_bounds__(1024) void scan_kernel(int* __restrict__ cnt,
                                                    int* __restrict__ off, int n) {
    __shared__ int buf[1024];
    __shared__ int carry_s;
    int tid = threadIdx.x;
    if (tid == 0) { carry_s = 0; off[0] = 0; }
    __syncthreads();
    for (int base = 0; base < n; base += 1024) {
        int idx = base + tid;
        int val = (idx < n) ? cnt[idx] : 0;
        buf[tid] = val;
        __syncthreads();
        int x = val;
        for (int s = 1; s < 1024; s <<= 1) {
            int y = (tid >= s) ? buf[tid - s] : 0;
            __syncthreads();
            x += y;
            buf[tid] = x;
            __syncthreads();
        }
        int carry = carry_s;
        if (idx < n) {
            off[idx + 1] = carry + x;
            cnt[idx] = carry + x - val;
        }
        __syncthreads();
        if (tid == 1023) carry_s = carry + x;
        __syncthreads();
    }
}

__global__ __launch_bounds__(256) void fill_kernel(const int* __restrict__ src,
                                                   const int* __restrict__ dst,
                                                   int* __restrict__ cursor,
                                                   int* __restrict__ csr_src, int E) {
    int e = blockIdx.x * 256 + threadIdx.x;
    if (e < E) {
        int p = atomicAdd(&cursor[dst[e]], 1);
        csr_src[p] = src[e];
    }
}

// ---------------------------------------------------------------------------
// packed weight transpose+convert: ONE kernel for all 14 weights
// ---------------------------------------------------------------------------
template <int KW, int NW, int KTOT, int KOFF>
__device__ __forceinline__ void tpose(int local, const float* __restrict__ W,
                                      bf16* __restrict__ Wt) {
    constexpr int SH = (KW == 128) ? 7 : ((KW == 256) ? 8 : 9);
    int n = local >> SH;
    int k = local & (KW - 1);
    Wt[(size_t)n * KTOT + KOFF + k] = __float2bfloat16(W[(size_t)k * NW + n]);
}

__global__ __launch_bounds__(256) void pack_weights_kernel(
    const float* s1_wr, const float* s1_wl, const float* s2_wr, const float* s2_wl,
    const float* t1_wq, const float* t1_wk, const float* t1_wv, const float* t1_ws,
    const float* t2_wq, const float* t2_wk, const float* t2_wv, const float* t2_ws,
    const float* p1_w, const float* p2_w,
    bf16* w1cat, bf16* w2cat, bf16* qw1, bf16* qw2, bf16* p1t, bf16* p2t) {
    int i = blockIdx.x * 256 + threadIdx.x;
    if (i < 16384)        tpose<128, 128, 256, 0>(i, s1_wr, w1cat);
    else if (i < 32768)   tpose<128, 128, 256, 128>(i - 16384, s1_wl, w1cat);
    else if (i < 65536)   tpose<128, 256, 256, 0>(i - 32768, s2_wr, w2cat);
    else if (i < 98304)   tpose<128, 256, 256, 128>(i - 65536, s2_wl, w2cat);
    else if (i < 163840)  tpose<256, 256, 256, 0>(i - 98304,  t1_wq, qw1);
    else if (i < 229376)  tpose<256, 256, 256, 0>(i - 163840, t1_wk, qw1 + 65536);
    else if (i < 294912)  tpose<256, 256, 256, 0>(i - 229376, t1_wv, qw1 + 131072);
    else if (i < 360448)  tpose<256, 256, 256, 0>(i - 294912, t1_ws, qw1 + 196608);
    else if (i < 425984)  tpose<256, 256, 256, 0>(i - 360448, t2_wq, qw2);
    else if (i < 491520)  tpose<256, 256, 256, 0>(i - 425984, t2_wk, qw2 + 65536);
    else if (i < 557056)  tpose<256, 256, 256, 0>(i - 491520, t2_wv, qw2 + 131072);
    else if (i < 622592)  tpose<256, 256, 256, 0>(i - 557056, t2_ws, qw2 + 196608);
    else if (i < 753664)  tpose<256, 512, 256, 0>(i - 622592, p1_w, p1t);
    else if (i < 819200)  tpose<512, 128, 512, 0>(i - 753664, p2_w, p2t);
}

__global__ __launch_bounds__(256) void pack_bias_kernel(
    const float* b1q, const float* b1k, const float* b1v, const float* b1s,
    const float* b2q, const float* b2k, const float* b2v, const float* b2s,
    float* qb1, float* qb2) {
    int i = blockIdx.x * 256 + threadIdx.x;
    if (i >= 2048) return;
    float* dst = (i < 1024) ? qb1 : qb2;
    int j = i & 1023;
    const float* s;
    if (i < 1024) s = (j < 256) ? b1q : (j < 512) ? b1k : (j < 768) ? b1v : b1s;
    else          s = (j < 256) ? b2q : (j < 512) ? b2k : (j < 768) ? b2v : b2s;
    dst[j] = s[j & 255];
}

// fp32 [rows,128] -> bf16 strided rows
__global__ __launch_bounds__(256) void conv2_kernel(const float* __restrict__ in,
                                                    bf16* __restrict__ out, int n, int ostride) {
    int i = blockIdx.x * 256 + threadIdx.x;
    if (i < n) {
        int r = i >> 7, c = i & 127;
        out[(size_t)r * ostride + c] = __float2bfloat16(in[i]);
    }
}

// ---------------------------------------------------------------------------
// Mean aggregation: 4 nodes/block, 1 wave/node, bf16x2/lane, unroll x4.
// ---------------------------------------------------------------------------
__global__ __launch_bounds__(256) void mean2_kernel(const bf16* __restrict__ x, int xstride,
                                                    const int* __restrict__ off,
                                                    const int* __restrict__ csr_src,
                                                    bf16* __restrict__ outp, int ostride) {
    int node = blockIdx.x * 4 + (threadIdx.x >> 6);
    int lane = threadIdx.x & 63;
    int e0 = off[node], e1 = off[node + 1];
    float s0 = 0.f, s1 = 0.f;
    int e = e0;
    for (; e + 3 < e1; e += 4) {
        int sa = csr_src[e], sb = csr_src[e + 1], sc = csr_src[e + 2], sd = csr_src[e + 3];
        uint a = *(const uint*)(x + (size_t)sa * xstride + lane * 2);
        uint b = *(const uint*)(x + (size_t)sb * xstride + lane * 2);
        uint c = *(const uint*)(x + (size_t)sc * xstride + lane * 2);
        uint d = *(const uint*)(x + (size_t)sd * xstride + lane * 2);
        union { uint i; float f; } t;
        t.i = a << 16; s0 += t.f; t.i = a & 0xffff0000u; s1 += t.f;
        t.i = b << 16; s0 += t.f; t.i = b & 0xffff0000u; s1 += t.f;
        t.i = c << 16; s0 += t.f; t.i = c & 0xffff0000u; s1 += t.f;
        t.i = d << 16; s0 += t.f; t.i = d & 0xffff0000u; s1 += t.f;
    }
    for (; e < e1; e++) {
        int sa = csr_src[e];
        uint a = *(const uint*)(x + (size_t)sa * xstride + lane * 2);
        union { uint i; float f; } t;
        t.i = a << 16; s0 += t.f; t.i = a & 0xffff0000u; s1 += t.f;
    }
    int deg = e1 - e0;
    float inv = (deg > 0) ? 1.f / (float)deg : 0.f;
    uint r = ((uint)f2bfr(s1 * inv) << 16) | (uint)f2bfr(s0 * inv);
    *(uint*)(outp + (size_t)node * ostride + lane * 2) = r;
}

// ---------------------------------------------------------------------------
// bf16 MFMA GEMM: C[M,N] = A[M,K] @ Wt[N,K]^T, fused epilogue.
// MODE 0: + bias, bf16 out.  MODE 2: relu(+bias), bf16.  MODE 3: sigmoid, fp32.
// TM=128: 4 waves 2x2 of 64x64, acc[4][4].  TM=64: 4 waves 64x32, acc[4][2].
// BK=32, 16x16x32 MFMA. Requires N%128==0, K%32==0.
// ---------------------------------------------------------------------------
template <int MODE, int TM>
__global__ __launch_bounds__(256, 2) void gemm_kernel(const bf16* __restrict__ A,
                                                      const bf16* __restrict__ Wt,
                                                      const float* __restrict__ bias,
                                                      void* __restrict__ Cv,
                                                      int M, int K, int N, int cstride) {
    constexpr int NT = (TM == 128) ? 4 : 2;   // n-tiles per wave
    __shared__ short As[TM * 32];
    __shared__ short Bs[128 * 32];
    int t = threadIdx.x;
    int lane = t & 63;
    int wave = t >> 6;
    int wm = (TM == 128) ? (wave >> 1) * 64 : 0;
    int wn = (TM == 128) ? (wave & 1) * 64 : wave * 32;
    int bm = blockIdx.y * TM, bn = blockIdx.x * 128;
    int quad = lane >> 4, l16 = lane & 15;
    int srow = t >> 2;
    int scol = (t & 3) * 8;

    f32x4 acc[4][NT];
    f32x4 zero = {0.f, 0.f, 0.f, 0.f};
    #pragma unroll
    for (int i = 0; i < 4; i++)
        #pragma unroll
        for (int j = 0; j < NT; j++) acc[i][j] = zero;

    for (int kk = 0; kk < K; kk += 32) {
        #pragma unroll
        for (int r = 0; r < TM / 64; r++) {
            int row = r * 64 + srow;
            int gm = bm + row; gm = (gm < M) ? gm : (M - 1);
            load_lds16(A + (size_t)gm * K + kk + scol, &As[row * 32 + scol]);
        }
        #pragma unroll
        for (int r = 0; r < 2; r++) {
            int row = r * 64 + srow;
            load_lds16(Wt + (size_t)(bn + row) * K + kk + scol, &Bs[row * 32 + scol]);
        }
        __syncthreads();
        short8 af[4], bfr[NT];
        #pragma unroll
        for (int i = 0; i < 4; i++)
            af[i] = *(const short8*)&As[(wm + i * 16 + l16) * 32 + quad * 8];
        #pragma unroll
        for (int j = 0; j < NT; j++)
            bfr[j] = *(const short8*)&Bs[(wn + j * 16 + l16) * 32 + quad * 8];
        #pragma unroll
        for (int i = 0; i < 4; i++)
            #pragma unroll
            for (int j = 0; j < NT; j++)
                acc[i][j] = __builtin_amdgcn_mfma_f32_16x16x32_bf16(af[i], bfr[j], acc[i][j], 0, 0, 0);
        __syncthreads();
    }

    #pragma unroll
    for (int i = 0; i < 4; i++) {
        int gm0 = bm + wm + i * 16 + quad * 4;
        #pragma unroll
        for (int j = 0; j < NT; j++) {
            int gn = bn + wn + j * 16 + l16;
            #pragma unroll
            for (int r = 0; r < 4; r++) {
                int gm = gm0 + r;
                if (gm >= M) continue;
                float v = acc[i][j][r] + bias[gn];
                if (MODE == 2) v = fmaxf(v, 0.f);
                if (MODE == 3) {
                    v = 1.f / (1.f + expf(-v));
                    ((float*)Cv)[(size_t)gm * cstride + gn] = v;
                } else {
                    ((bf16*)Cv)[(size_t)gm * cstride + gn] = __float2bfloat16(v);
                }
            }
        }
    }
}

template <int MODE, int TM>
static void launch_gemm(const bf16* A, const bf16* Wt, const float* bias, void* C,
                        int M, int K, int N, int cstride, hipStream_t st) {
    dim3 grid(N / 128, (M + TM - 1) / TM);
    hipLaunchKernelGGL((gemm_kernel<MODE, TM>), grid, dim3(256), 0, st, A, Wt, bias, C, M, K, N, cstride);
}

// ---------------------------------------------------------------------------
// TransformerConv attention: 3-phase chunked online softmax.
// qkvs row stride 1024: [q(256) k(256) v(256) skip(256)]. Block = 1 node.
// ---------------------------------------------------------------------------
__global__ __launch_bounds__(256) void attn2_kernel(const bf16* __restrict__ qkvs,
                                                    const int* __restrict__ off,
                                                    const int* __restrict__ csr_src,
                                                    bf16* __restrict__ out, int ostride) {
    __shared__ float lg[CH][9];
    __shared__ float pp[CH][9];
    __shared__ int srcs[CH];
    int i = blockIdx.x;
    int tid = threadIdx.x;
    int ea = tid >> 4, ha = (tid >> 1) & 7, half = tid & 1;
    int hc = tid >> 5, dc = tid & 31;

    float qf[16];
    {
        const short8* qp = (const short8*)(qkvs + (size_t)i * 1024 + ha * 32 + half * 16);
        #pragma unroll
        for (int c = 0; c < 2; c++) {
            short8 v = qp[c];
            #pragma unroll
            for (int j = 0; j < 8; j++) qf[c * 8 + j] = bfr2f((ushort)v[j]);
        }
    }

    int e0 = off[i], e1 = off[i + 1];
    float m = -INFINITY, l = 0.f, acc = 0.f;
    for (int base = e0; base < e1; base += CH) {
        int cnt = min(CH, e1 - base);
        // ---- A: logits ----
        int s = 0;
        if (ea < cnt) s = csr_src[base + ea];
        if ((tid & 15) == 0) srcs[ea] = s;
        if (ea < cnt) {
            const short8* kp = (const short8*)(qkvs + (size_t)s * 1024 + 256 + ha * 32 + half * 16);
            float d = 0.f;
            #pragma unroll
            for (int c = 0; c < 2; c++) {
                short8 kv = kp[c];
                #pragma unroll
                for (int j = 0; j < 8; j++) d += qf[c * 8 + j] * bfr2f((ushort)kv[j]);
            }
            d += __shfl_xor(d, 1);
            if (half == 0) lg[ea][ha] = d * 0.17677669529663687f;  // 1/sqrt(32)
        }
        __syncthreads();
        // ---- B: per-head softmax merge (exp once per edge-head) ----
        float lo = (dc < cnt) ? lg[dc][hc] : -INFINITY;
        float cm = lo;
        #pragma unroll
        for (int w = 16; w >= 1; w >>= 1) cm = fmaxf(cm, __shfl_xor(cm, w, 32));
        float mn = fmaxf(m, cm);
        float alpha = __expf(m - mn);
        float p = (dc < cnt) ? __expf(lo - mn) : 0.f;
        if (dc < CH) pp[dc][hc] = p;
        float ps = p;
        #pragma unroll
        for (int w = 16; w >= 1; w >>= 1) ps += __shfl_xor(ps, w, 32);
        l = l * alpha + ps;
        m = mn;
        __syncthreads();
        // ---- C: weighted V accumulation, unroll x4 (pp zero-padded) ----
        acc *= alpha;
        for (int e = 0; e < cnt; e += 4) {
            float p0 = pp[e][hc],     p1 = pp[e + 1][hc];
            float p2 = pp[e + 2][hc], p3 = pp[e + 3][hc];
            int s0 = srcs[e],     s1 = srcs[e + 1];
            int s2 = srcs[e + 2], s3 = srcs[e + 3];
            float v0 = bfr2f(*(const ushort*)(qkvs + (size_t)s0 * 1024 + 512 + tid));
            float v1 = bfr2f(*(const ushort*)(qkvs + (size_t)s1 * 1024 + 512 + tid));
            float v2 = bfr2f(*(const ushort*)(qkvs + (size_t)s2 * 1024 + 512 + tid));
            float v3 = bfr2f(*(const ushort*)(qkvs + (size_t)s3 * 1024 + 512 + tid));
            acc += p0 * v0 + p1 * v1 + p2 * v2 + p3 * v3;
        }
        __syncthreads();
    }
    float res = (l > 0.f) ? acc / l : 0.f;
    float val = res + bfr2f(*(const ushort*)(qkvs + (size_t)i * 1024 + 768 + tid));
    out[(size_t)i * ostride + tid] = __float2bfloat16(fmaxf(val, 0.f));
}

// ---------------------------------------------------------------------------
// Global max pool over sorted batch.
// ---------------------------------------------------------------------------
__global__ __launch_bounds__(128) void pool_kernel(const float* __restrict__ hfin,
                                                   const int* __restrict__ batch,
                                                   float* __restrict__ out) {
    int f = threadIdx.x;
    int i0 = blockIdx.x * 64;
    int i1 = i0 + 64;
    if (i1 > NN) i1 = NN;
    int cur_g = -1;
    float cur_max = 0.f;
    for (int i = i0; i < i1; i++) {
        int g = batch[i];
        float val = hfin[(size_t)i * 128 + f];
        if (g != cur_g) {
            if (cur_g >= 0) atomicMax((int*)&out[cur_g * 128 + f], __float_as_int(cur_max));
            cur_g = g;
            cur_max = val;
        } else {
            cur_max = fmaxf(cur_max, val);
        }
    }
    if (cur_g >= 0) atomicMax((int*)&out[cur_g * 128 + f], __float_as_int(cur_max));
}

// ---------------------------------------------------------------------------
extern "C" void kernel_launch(void* const* d_in, const int* in_sizes, int n_in,
                              void* d_out, int out_size, void* d_ws, size_t ws_size,
                              hipStream_t stream) {
    const float* x      = (const float*)d_in[0];
    const int*   ei     = (const int*)d_in[1];
    const int*   batch  = (const int*)d_in[2];
    const float* s1_wl  = (const float*)d_in[3];
    const float* s1_bl  = (const float*)d_in[4];
    const float* s1_wr  = (const float*)d_in[5];
    const float* s2_wl  = (const float*)d_in[6];
    const float* s2_bl  = (const float*)d_in[7];
    const float* s2_wr  = (const float*)d_in[8];
    const float* t1_wq  = (const float*)d_in[9];
    const float* t1_bq  = (const float*)d_in[10];
    const float* t1_wk  = (const float*)d_in[11];
    const float* t1_bk  = (const float*)d_in[12];
    const float* t1_wv  = (const float*)d_in[13];
    const float* t1_bv  = (const float*)d_in[14];
    const float* t1_ws  = (const float*)d_in[15];
    const float* t1_bs  = (const float*)d_in[16];
    const float* t2_wq  = (const float*)d_in[17];
    const float* t2_bq  = (const float*)d_in[18];
    const float* t2_wk  = (const float*)d_in[19];
    const float* t2_bk  = (const float*)d_in[20];
    const float* t2_wv  = (const float*)d_in[21];
    const float* t2_bv  = (const float*)d_in[22];
    const float* t2_wsk = (const float*)d_in[23];
    const float* t2_bs  = (const float*)d_in[24];
    const float* p1_w   = (const float*)d_in[25];
    const float* p1_b   = (const float*)d_in[26];
    const float* p2_w   = (const float*)d_in[27];
    const float* p2_b   = (const float*)d_in[28];
    float* out = (float*)d_out;

    // ---- workspace layout ----
    char* ws = (char*)d_ws;
    size_t o = 0;
    auto alloc = [&](size_t bytes) { char* p = ws + o; o += (bytes + 255) & ~(size_t)255; return p; };
    int* off     = (int*)alloc(sizeof(int) * (NN + 1));
    int* cursor  = (int*)alloc(sizeof(int) * NN);
    int* csr_src = (int*)alloc(sizeof(int) * EE);
    bf16* w1cat = (bf16*)alloc(2 * 128 * 256);
    bf16* w2cat = (bf16*)alloc(2 * 256 * 256);
    bf16* qw1   = (bf16*)alloc(2 * 1024 * 256);
    bf16* qw2   = (bf16*)alloc(2 * 1024 * 256);
    bf16* p1t   = (bf16*)alloc(2 * 512 * 256);
    bf16* p2t   = (bf16*)alloc(2 * 128 * 512);
    float* qb1  = (float*)alloc(4 * 1024);
    float* qb2  = (float*)alloc(4 * 1024);
    bf16* xm1   = (bf16*)alloc(2 * (size_t)NN * 256);   // [x | mean(x)]; later h2/h4
    bf16* xm2   = (bf16*)alloc(2 * (size_t)NN * 256);   // [h1 | mean(h1)]
    bf16* t1b   = (bf16*)alloc(2 * (size_t)NN * 512);   // t1 (stride 256); later p1o
    bf16* Q     = (bf16*)alloc(2 * (size_t)NN * 1024);  // qkvs; later hfin (fp32)
    bf16* h2   = xm1;
    bf16* t1   = t1b;
    bf16* h4   = xm1;
    bf16* p1o  = t1b;
    float* hfin = (float*)Q;

    const int* src = ei;
    const int* dst = ei + EE;

    // ---- weight/bias packing (2 dispatches) ----
    pack_weights_kernel<<<3200, 256, 0, stream>>>(
        s1_wr, s1_wl, s2_wr, s2_wl,
        t1_wq, t1_wk, t1_wv, t1_ws,
        t2_wq, t2_wk, t2_wv, t2_wsk,
        p1_w, p2_w,
        w1cat, w2cat, qw1, qw2, p1t, p2t);
    pack_bias_kernel<<<8, 256, 0, stream>>>(t1_bq, t1_bk, t1_bv, t1_bs,
                                            t2_bq, t2_bk, t2_bv, t2_bs, qb1, qb2);

    // x -> xm1 first half (stride 256)
    conv2_kernel<<<(NN * 128 + 255) / 256, 256, 0, stream>>>(x, xm1, NN * 128, 256);

    // ---- CSR build ----
    hipMemsetAsync(cursor, 0, sizeof(int) * NN, stream);
    count_kernel<<<(EE + 255) / 256, 256, 0, stream>>>(dst, cursor, EE);
    scan_kernel<<<1, 1024, 0, stream>>>(cursor, off, NN);
    fill_kernel<<<(EE + 255) / 256, 256, 0, stream>>>(src, dst, cursor, csr_src, EE);

    // ---- SAGE 1: h1 = relu([x|mean(x)] @ w1cat + bl) -> xm2 first half ----
    mean2_kernel<<<NN / 4, 256, 0, stream>>>(xm1, 256, off, csr_src, xm1 + 128, 256);
    launch_gemm<2, 64>(xm1, w1cat, s1_bl, xm2, NN, 256, 128, 256, stream);

    // ---- SAGE 2: h2 = relu([h1|mean(h1)] @ w2cat + bl) ----
    mean2_kernel<<<NN / 4, 256, 0, stream>>>(xm2, 256, off, csr_src, xm2 + 128, 256);
    launch_gemm<2, 64>(xm2, w2cat, s2_bl, h2, NN, 256, 256, 256, stream);

    // ---- TransformerConv 1 ----
    launch_gemm<0, 128>(h2, qw1, qb1, Q, NN, 256, 1024, 1024, stream);
    attn2_kernel<<<NN, 256, 0, stream>>>(Q, off, csr_src, t1, 256);

    // ---- TransformerConv 2 ----
    launch_gemm<0, 128>(t1, qw2, qb2, Q, NN, 256, 1024, 1024, stream);
    attn2_kernel<<<NN, 256, 0, stream>>>(Q, off, csr_src, h4, 256);

    // ---- proj MLP ----
    launch_gemm<2, 128>(h4, p1t, p1_b, p1o, NN, 256, 512, 512, stream);
    launch_gemm<3, 64>(p1o, p2t, p2_b, hfin, NN, 512, 128, 128, stream);

    // ---- global max pool ----
    hipMemsetAsync(out, 0, sizeof(float) * (size_t)out_size, stream);
    pool_kernel<<<(NN + 63) / 64, 128, 0, stream>>>(hfin, batch, out);
}

// Round 5
// 475.559 us; speedup vs baseline: 2.7713x; 1.0351x over previous
//
#include <hip/hip_runtime.h>
#include <hip/hip_bf16.h>
#include <math.h>

#define NN 20000
#define EE 320000
#define GG 64
#define CH 16   // attention chunk size (edges)

typedef __hip_bfloat16 bf16;
typedef __attribute__((ext_vector_type(8))) short short8;
typedef __attribute__((ext_vector_type(4))) float f32x4;
typedef unsigned int uint;
typedef unsigned short ushort;

__device__ __forceinline__ float bfr2f(ushort u) {
    union { uint i; float f; } c; c.i = ((uint)u) << 16; return c.f;
}
__device__ __forceinline__ ushort f2bfr(float f) {
    bf16 h = __float2bfloat16(f);
    return *(ushort*)&h;
}

// ---------------------------------------------------------------------------
// async global->LDS 16B copy
// ---------------------------------------------------------------------------
__device__ __forceinline__ void load_lds16(const void* g, void* l) {
    __builtin_amdgcn_global_load_lds(
        (const __attribute__((address_space(1))) unsigned int*)g,
        (__attribute__((address_space(3))) unsigned int*)l, 16, 0, 0);
}

// ---------------------------------------------------------------------------
// fused prep: x->bf16 (strided), 14 weight transposes, bias packs, CSR count
// ---------------------------------------------------------------------------
template <int KW, int NW, int KTOT, int KOFF>
__device__ __forceinline__ void tpose(int local, const float* __restrict__ W,
                                      bf16* __restrict__ Wt) {
    constexpr int SH = (KW == 128) ? 7 : ((KW == 256) ? 8 : 9);
    int n = local >> SH;
    int k = local & (KW - 1);
    Wt[(size_t)n * KTOT + KOFF + k] = __float2bfloat16(W[(size_t)k * NW + n]);
}

#define PREP_CONV  10000        // NN*128/256
#define PREP_PACK  (PREP_CONV + 3200)
#define PREP_BIAS  (PREP_PACK + 8)
#define PREP_COUNT (PREP_BIAS + 1250)

__global__ __launch_bounds__(256) void prep_kernel(
    const float* x, bf16* xm1,
    const float* s1_wr, const float* s1_wl, const float* s2_wr, const float* s2_wl,
    const float* t1_wq, const float* t1_wk, const float* t1_wv, const float* t1_ws,
    const float* t2_wq, const float* t2_wk, const float* t2_wv, const float* t2_ws,
    const float* p1_w, const float* p2_w,
    bf16* w1cat, bf16* w2cat, bf16* qw1, bf16* qw2, bf16* p1t, bf16* p2t,
    const float* b1q, const float* b1k, const float* b1v, const float* b1s,
    const float* b2q, const float* b2k, const float* b2v, const float* b2s,
    float* qb1, float* qb2,
    const int* dst, int* cnt) {
    int bid = blockIdx.x;
    int tid = threadIdx.x;
    if (bid < PREP_CONV) {
        int i = bid * 256 + tid;  // < NN*128
        int r = i >> 7, c = i & 127;
        xm1[(size_t)r * 256 + c] = __float2bfloat16(x[i]);
    } else if (bid < PREP_PACK) {
        int i = (bid - PREP_CONV) * 256 + tid;
        if (i < 16384)        tpose<128, 128, 256, 0>(i, s1_wr, w1cat);
        else if (i < 32768)   tpose<128, 128, 256, 128>(i - 16384, s1_wl, w1cat);
        else if (i < 65536)   tpose<128, 256, 256, 0>(i - 32768, s2_wr, w2cat);
        else if (i < 98304)   tpose<128, 256, 256, 128>(i - 65536, s2_wl, w2cat);
        else if (i < 163840)  tpose<256, 256, 256, 0>(i - 98304,  t1_wq, qw1);
        else if (i < 229376)  tpose<256, 256, 256, 0>(i - 163840, t1_wk, qw1 + 65536);
        else if (i < 294912)  tpose<256, 256, 256, 0>(i - 229376, t1_wv, qw1 + 131072);
        else if (i < 360448)  tpose<256, 256, 256, 0>(i - 294912, t1_ws, qw1 + 196608);
        else if (i < 425984)  tpose<256, 256, 256, 0>(i - 360448, t2_wq, qw2);
        else if (i < 491520)  tpose<256, 256, 256, 0>(i - 425984, t2_wk, qw2 + 65536);
        else if (i < 557056)  tpose<256, 256, 256, 0>(i - 491520, t2_wv, qw2 + 131072);
        else if (i < 622592)  tpose<256, 256, 256, 0>(i - 557056, t2_ws, qw2 + 196608);
        else if (i < 753664)  tpose<256, 512, 256, 0>(i - 622592, p1_w, p1t);
        else if (i < 819200)  tpose<512, 128, 512, 0>(i - 753664, p2_w, p2t);
    } else if (bid < PREP_BIAS) {
        int i = (bid - PREP_PACK) * 256 + tid;
        if (i < 2048) {
            float* d = (i < 1024) ? qb1 : qb2;
            int j = i & 1023;
            const float* s;
            if (i < 1024) s = (j < 256) ? b1q : (j < 512) ? b1k : (j < 768) ? b1v : b1s;
            else          s = (j < 256) ? b2q : (j < 512) ? b2k : (j < 768) ? b2v : b2s;
            d[j] = s[j & 255];
        }
    } else {
        int e = (bid - PREP_BIAS) * 256 + tid;
        if (e < EE) atomicAdd(&cnt[dst[e]], 1);
    }
}

// ---------------------------------------------------------------------------
// scan: shfl-based wave scan, 3 barriers/iter. cnt -> off (excl), cursor.
// ---------------------------------------------------------------------------
__global__ __launch_bounds__(1024) void scan_kernel(int* __restrict__ cnt,
                                                    int* __restrict__ off, int n) {
    __shared__ int wsum[16];
    __shared__ int carry_s;
    int tid = threadIdx.x;
    int lane = tid & 63, wid = tid >> 6;
    if (tid == 0) { carry_s = 0; off[0] = 0; }
    __syncthreads();
    for (int base = 0; base < n; base += 1024) {
        int idx = base + tid;
        int val = (idx < n) ? cnt[idx] : 0;
        int x = val;
        #pragma unroll
        for (int s = 1; s < 64; s <<= 1) {
            int y = __shfl_up(x, s, 64);
            if (lane >= s) x += y;
        }
        if (lane == 63) wsum[wid] = x;
        __syncthreads();
        if (tid == 0) {
            int c = carry_s;
            #pragma unroll
            for (int w = 0; w < 16; w++) { int t = wsum[w]; wsum[w] = c; c += t; }
            carry_s = c;
        }
        __syncthreads();
        int incl = wsum[wid] + x;
        if (idx < n) {
            off[idx + 1] = incl;
            cnt[idx] = incl - val;
        }
        __syncthreads();
    }
}

__global__ __launch_bounds__(256) void fill_kernel(const int* __restrict__ src,
                                                   const int* __restrict__ dst,
                                                   int* __restrict__ cursor,
                                                   int* __restrict__ csr_src, int E) {
    int e = blockIdx.x * 256 + threadIdx.x;
    if (e < E) {
        int p = atomicAdd(&cursor[dst[e]], 1);
        csr_src[p] = src[e];
    }
}

// ---------------------------------------------------------------------------
// Mean aggregation: 4 nodes/block, 1 wave/node, bf16x2/lane, unroll x8.
// ---------------------------------------------------------------------------
__global__ __launch_bounds__(256) void mean2_kernel(const bf16* __restrict__ x, int xstride,
                                                    const int* __restrict__ off,
                                                    const int* __restrict__ csr_src,
                                                    bf16* __restrict__ outp, int ostride) {
    int node = blockIdx.x * 4 + (threadIdx.x >> 6);
    int lane = threadIdx.x & 63;
    int e0 = off[node], e1 = off[node + 1];
    float s0 = 0.f, s1 = 0.f;
    int e = e0;
    for (; e + 7 < e1; e += 8) {
        uint a[8];
        #pragma unroll
        for (int j = 0; j < 8; j++) {
            int sa = csr_src[e + j];
            a[j] = *(const uint*)(x + (size_t)sa * xstride + lane * 2);
        }
        #pragma unroll
        for (int j = 0; j < 8; j++) {
            union { uint i; float f; } t;
            t.i = a[j] << 16; s0 += t.f;
            t.i = a[j] & 0xffff0000u; s1 += t.f;
        }
    }
    for (; e < e1; e++) {
        int sa = csr_src[e];
        uint a = *(const uint*)(x + (size_t)sa * xstride + lane * 2);
        union { uint i; float f; } t;
        t.i = a << 16; s0 += t.f; t.i = a & 0xffff0000u; s1 += t.f;
    }
    int deg = e1 - e0;
    float inv = (deg > 0) ? 1.f / (float)deg : 0.f;
    uint r = ((uint)f2bfr(s1 * inv) << 16) | (uint)f2bfr(s0 * inv);
    *(uint*)(outp + (size_t)node * ostride + lane * 2) = r;
}

// ---------------------------------------------------------------------------
// bf16 MFMA GEMM: C[M,N] = A[M,K] @ Wt[N,K]^T, fused epilogue. BK=64.
// MODE 0: + bias, bf16 out.  MODE 2: relu(+bias), bf16.
// MODE 4: sigmoid(+bias) then atomicMax-pool into pool_out[batch[m]*128+n].
// TM=128: 4 waves 2x2 of 64x64.  TM=64: 4 waves of 64x32.
// ---------------------------------------------------------------------------
template <int MODE, int TM>
__global__ __launch_bounds__(256, 2) void gemm_kernel(const bf16* __restrict__ A,
                                                      const bf16* __restrict__ Wt,
                                                      const float* __restrict__ bias,
                                                      void* __restrict__ Cv,
                                                      int M, int K, int N, int cstride,
                                                      const int* __restrict__ batch,
                                                      float* __restrict__ pool_out) {
    constexpr int NT = (TM == 128) ? 4 : 2;   // n-tiles per wave
    __shared__ short As[TM * 64];
    __shared__ short Bs[128 * 64];
    int t = threadIdx.x;
    int lane = t & 63;
    int wave = t >> 6;
    int wm = (TM == 128) ? (wave >> 1) * 64 : 0;
    int wn = (TM == 128) ? (wave & 1) * 64 : wave * 32;
    int bm = blockIdx.y * TM, bn = blockIdx.x * 128;
    int quad = lane >> 4, l16 = lane & 15;
    int srow = t >> 3;           // 32 staging rows per round
    int scol = (t & 7) * 8;      // 64 cols in 8x 16B chunks

    f32x4 acc[4][NT];
    f32x4 zero = {0.f, 0.f, 0.f, 0.f};
    #pragma unroll
    for (int i = 0; i < 4; i++)
        #pragma unroll
        for (int j = 0; j < NT; j++) acc[i][j] = zero;

    for (int kk = 0; kk < K; kk += 64) {
        #pragma unroll
        for (int r = 0; r < TM / 32; r++) {
            int row = r * 32 + srow;
            int gm = bm + row; gm = (gm < M) ? gm : (M - 1);
            load_lds16(A + (size_t)gm * K + kk + scol, &As[row * 64 + scol]);
        }
        #pragma unroll
        for (int r = 0; r < 4; r++) {
            int row = r * 32 + srow;
            load_lds16(Wt + (size_t)(bn + row) * K + kk + scol, &Bs[row * 64 + scol]);
        }
        __syncthreads();
        #pragma unroll
        for (int ks = 0; ks < 2; ks++) {
            short8 af[4], bfr[NT];
            #pragma unroll
            for (int i = 0; i < 4; i++)
                af[i] = *(const short8*)&As[(wm + i * 16 + l16) * 64 + ks * 32 + quad * 8];
            #pragma unroll
            for (int j = 0; j < NT; j++)
                bfr[j] = *(const short8*)&Bs[(wn + j * 16 + l16) * 64 + ks * 32 + quad * 8];
            #pragma unroll
            for (int i = 0; i < 4; i++)
                #pragma unroll
                for (int j = 0; j < NT; j++)
                    acc[i][j] = __builtin_amdgcn_mfma_f32_16x16x32_bf16(af[i], bfr[j], acc[i][j], 0, 0, 0);
        }
        __syncthreads();
    }

    // epilogue: C/D layout col=lane&15, row=quad*4+reg
    #pragma unroll
    for (int i = 0; i < 4; i++) {
        int gm0 = bm + wm + i * 16 + quad * 4;
        #pragma unroll
        for (int j = 0; j < NT; j++) {
            int gn = bn + wn + j * 16 + l16;
            #pragma unroll
            for (int r = 0; r < 4; r++) {
                int gm = gm0 + r;
                if (gm >= M) continue;
                float v = acc[i][j][r] + bias[gn];
                if (MODE == 2) v = fmaxf(v, 0.f);
                if (MODE == 4) {
                    v = 1.f / (1.f + expf(-v));
                    atomicMax((int*)&pool_out[batch[gm] * 128 + gn], __float_as_int(v));
                } else {
                    ((bf16*)Cv)[(size_t)gm * cstride + gn] = __float2bfloat16(v);
                }
            }
        }
    }
}

template <int MODE, int TM>
static void launch_gemm(const bf16* A, const bf16* Wt, const float* bias, void* C,
                        int M, int K, int N, int cstride, hipStream_t st,
                        const int* batch = nullptr, float* pool_out = nullptr) {
    dim3 grid(N / 128, (M + TM - 1) / TM);
    hipLaunchKernelGGL((gemm_kernel<MODE, TM>), grid, dim3(256), 0, st,
                       A, Wt, bias, C, M, K, N, cstride, batch, pool_out);
}

// ---------------------------------------------------------------------------
// TransformerConv attention: 3-phase chunked online softmax, phase C x8.
// qkvs row stride 1024: [q(256) k(256) v(256) skip(256)]. Block = 1 node.
// ---------------------------------------------------------------------------
__global__ __launch_bounds__(256) void attn2_kernel(const bf16* __restrict__ qkvs,
                                                    const int* __restrict__ off,
                                                    const int* __restrict__ csr_src,
                                                    bf16* __restrict__ out, int ostride) {
    __shared__ float lg[CH][9];
    __shared__ float pp[CH][9];
    __shared__ int srcs[CH];
    int i = blockIdx.x;
    int tid = threadIdx.x;
    int ea = tid >> 4, ha = (tid >> 1) & 7, half = tid & 1;
    int hc = tid >> 5, dc = tid & 31;

    float qf[16];
    {
        const short8* qp = (const short8*)(qkvs + (size_t)i * 1024 + ha * 32 + half * 16);
        #pragma unroll
        for (int c = 0; c < 2; c++) {
            short8 v = qp[c];
            #pragma unroll
            for (int j = 0; j < 8; j++) qf[c * 8 + j] = bfr2f((ushort)v[j]);
        }
    }

    int e0 = off[i], e1 = off[i + 1];
    float m = -INFINITY, l = 0.f, acc = 0.f;
    for (int base = e0; base < e1; base += CH) {
        int cnt = min(CH, e1 - base);
        // ---- A: logits ----
        int s = 0;
        if (ea < cnt) s = csr_src[base + ea];
        if ((tid & 15) == 0) srcs[ea] = s;
        if (ea < cnt) {
            const short8* kp = (const short8*)(qkvs + (size_t)s * 1024 + 256 + ha * 32 + half * 16);
            float d = 0.f;
            #pragma unroll
            for (int c = 0; c < 2; c++) {
                short8 kv = kp[c];
                #pragma unroll
                for (int j = 0; j < 8; j++) d += qf[c * 8 + j] * bfr2f((ushort)kv[j]);
            }
            d += __shfl_xor(d, 1);
            if (half == 0) lg[ea][ha] = d * 0.17677669529663687f;  // 1/sqrt(32)
        }
        __syncthreads();
        // ---- B: per-head softmax merge (exp once per edge-head) ----
        float lo = (dc < cnt) ? lg[dc][hc] : -INFINITY;
        float cm = lo;
        #pragma unroll
        for (int w = 16; w >= 1; w >>= 1) cm = fmaxf(cm, __shfl_xor(cm, w, 32));
        float mn = fmaxf(m, cm);
        float alpha = __expf(m - mn);
        float p = (dc < cnt) ? __expf(lo - mn) : 0.f;
        if (dc < CH) pp[dc][hc] = p;
        float ps = p;
        #pragma unroll
        for (int w = 16; w >= 1; w >>= 1) ps += __shfl_xor(ps, w, 32);
        l = l * alpha + ps;
        m = mn;
        __syncthreads();
        // ---- C: weighted V accumulation, unroll x8 (pp/srcs zero-padded) ----
        acc *= alpha;
        for (int e = 0; e < cnt; e += 8) {
            float pv[8];
            int sv[8];
            float vv[8];
            #pragma unroll
            for (int j = 0; j < 8; j++) { pv[j] = pp[e + j][hc]; sv[j] = srcs[e + j]; }
            #pragma unroll
            for (int j = 0; j < 8; j++)
                vv[j] = bfr2f(*(const ushort*)(qkvs + (size_t)sv[j] * 1024 + 512 + tid));
            #pragma unroll
            for (int j = 0; j < 8; j++) acc += pv[j] * vv[j];
        }
        __syncthreads();
    }
    float res = (l > 0.f) ? acc / l : 0.f;
    float val = res + bfr2f(*(const ushort*)(qkvs + (size_t)i * 1024 + 768 + tid));
    out[(size_t)i * ostride + tid] = __float2bfloat16(fmaxf(val, 0.f));
}

// ---------------------------------------------------------------------------
extern "C" void kernel_launch(void* const* d_in, const int* in_sizes, int n_in,
                              void* d_out, int out_size, void* d_ws, size_t ws_size,
                              hipStream_t stream) {
    const float* x      = (const float*)d_in[0];
    const int*   ei     = (const int*)d_in[1];
    const int*   batch  = (const int*)d_in[2];
    const float* s1_wl  = (const float*)d_in[3];
    const float* s1_bl  = (const float*)d_in[4];
    const float* s1_wr  = (const float*)d_in[5];
    const float* s2_wl  = (const float*)d_in[6];
    const float* s2_bl  = (const float*)d_in[7];
    const float* s2_wr  = (const float*)d_in[8];
    const float* t1_wq  = (const float*)d_in[9];
    const float* t1_bq  = (const float*)d_in[10];
    const float* t1_wk  = (const float*)d_in[11];
    const float* t1_bk  = (const float*)d_in[12];
    const float* t1_wv  = (const float*)d_in[13];
    const float* t1_bv  = (const float*)d_in[14];
    const float* t1_ws  = (const float*)d_in[15];
    const float* t1_bs  = (const float*)d_in[16];
    const float* t2_wq  = (const float*)d_in[17];
    const float* t2_bq  = (const float*)d_in[18];
    const float* t2_wk  = (const float*)d_in[19];
    const float* t2_bk  = (const float*)d_in[20];
    const float* t2_wv  = (const float*)d_in[21];
    const float* t2_bv  = (const float*)d_in[22];
    const float* t2_wsk = (const float*)d_in[23];
    const float* t2_bs  = (const float*)d_in[24];
    const float* p1_w   = (const float*)d_in[25];
    const float* p1_b   = (const float*)d_in[26];
    const float* p2_w   = (const float*)d_in[27];
    const float* p2_b   = (const float*)d_in[28];
    float* out = (float*)d_out;

    // ---- workspace layout ----
    char* ws = (char*)d_ws;
    size_t o = 0;
    auto alloc = [&](size_t bytes) { char* p = ws + o; o += (bytes + 255) & ~(size_t)255; return p; };
    int* off     = (int*)alloc(sizeof(int) * (NN + 1));
    int* cursor  = (int*)alloc(sizeof(int) * NN);
    int* csr_src = (int*)alloc(sizeof(int) * EE);
    bf16* w1cat = (bf16*)alloc(2 * 128 * 256);
    bf16* w2cat = (bf16*)alloc(2 * 256 * 256);
    bf16* qw1   = (bf16*)alloc(2 * 1024 * 256);
    bf16* qw2   = (bf16*)alloc(2 * 1024 * 256);
    bf16* p1t   = (bf16*)alloc(2 * 512 * 256);
    bf16* p2t   = (bf16*)alloc(2 * 128 * 512);
    float* qb1  = (float*)alloc(4 * 1024);
    float* qb2  = (float*)alloc(4 * 1024);
    bf16* xm1   = (bf16*)alloc(2 * (size_t)NN * 256);   // [x | mean(x)]; later h2/h4
    bf16* xm2   = (bf16*)alloc(2 * (size_t)NN * 256);   // [h1 | mean(h1)]
    bf16* t1b   = (bf16*)alloc(2 * (size_t)NN * 512);   // t1 (stride 256); later p1o
    bf16* Q     = (bf16*)alloc(2 * (size_t)NN * 1024);  // qkvs
    bf16* h2   = xm1;
    bf16* t1   = t1b;
    bf16* h4   = xm1;
    bf16* p1o  = t1b;

    const int* src = ei;
    const int* dst = ei + EE;

    // ---- memsets (cursor for CSR count; out for pool atomicMax) ----
    hipMemsetAsync(cursor, 0, sizeof(int) * NN, stream);
    hipMemsetAsync(out, 0, sizeof(float) * (size_t)out_size, stream);

    // ---- fused prep: conv x + pack weights + pack biases + CSR count ----
    prep_kernel<<<PREP_COUNT, 256, 0, stream>>>(
        x, xm1,
        s1_wr, s1_wl, s2_wr, s2_wl,
        t1_wq, t1_wk, t1_wv, t1_ws,
        t2_wq, t2_wk, t2_wv, t2_wsk,
        p1_w, p2_w,
        w1cat, w2cat, qw1, qw2, p1t, p2t,
        t1_bq, t1_bk, t1_bv, t1_bs,
        t2_bq, t2_bk, t2_bv, t2_bs,
        qb1, qb2,
        dst, cursor);

    // ---- CSR scan + fill ----
    scan_kernel<<<1, 1024, 0, stream>>>(cursor, off, NN);
    fill_kernel<<<(EE + 255) / 256, 256, 0, stream>>>(src, dst, cursor, csr_src, EE);

    // ---- SAGE 1: h1 = relu([x|mean(x)] @ w1cat + bl) -> xm2 first half ----
    mean2_kernel<<<NN / 4, 256, 0, stream>>>(xm1, 256, off, csr_src, xm1 + 128, 256);
    launch_gemm<2, 64>(xm1, w1cat, s1_bl, xm2, NN, 256, 128, 256, stream);

    // ---- SAGE 2: h2 = relu([h1|mean(h1)] @ w2cat + bl) ----
    mean2_kernel<<<NN / 4, 256, 0, stream>>>(xm2, 256, off, csr_src, xm2 + 128, 256);
    launch_gemm<2, 64>(xm2, w2cat, s2_bl, h2, NN, 256, 256, 256, stream);

    // ---- TransformerConv 1 ----
    launch_gemm<0, 128>(h2, qw1, qb1, Q, NN, 256, 1024, 1024, stream);
    attn2_kernel<<<NN, 256, 0, stream>>>(Q, off, csr_src, t1, 256);

    // ---- TransformerConv 2 ----
    launch_gemm<0, 128>(t1, qw2, qb2, Q, NN, 256, 1024, 1024, stream);
    attn2_kernel<<<NN, 256, 0, stream>>>(Q, off, csr_src, h4, 256);

    // ---- proj MLP (p2 fuses sigmoid + global max pool) ----
    launch_gemm<2, 128>(h4, p1t, p1_b, p1o, NN, 256, 512, 512, stream);
    launch_gemm<4, 64>(p1o, p2t, p2_b, nullptr, NN, 512, 128, 128, stream, batch, out);
}